// Round 12
// baseline (3269.784 us; speedup 1.0000x reference)
//
#include <hip/hip_runtime.h>
#include <hip/hip_fp16.h>
#include <cmath>

static constexpr int   Bb     = 16;
static constexpr int   Nn     = 1024;
static constexpr int   Mm     = 1024;
static constexpr int   Dd     = 64;
static constexpr int   MAXIT  = 100;
static constexpr float THRESH = 1e-4f;
static constexpr float S2     = 144.26950408889634f;   // (1/eps)*log2(e) == 1/(eps*ln2)
static constexpr float EPSLN2 = 0.006931471805599453f; // eps*ln2
static constexpr float UAB    = -0.06931461565651f;    // eps*log(1/1024+1e-8)
static constexpr int SLOTS_PER_IT = 1024;              // fallback dslots stride

// LDS layout for persistent kernel (bytes) — STATIC shared (capture-safe)
static constexpr unsigned OFF_VS    = 131072;  // float[1024]
static constexpr unsigned OFF_XST   = 135168;  // float[4096] build-only; overlaid below
static constexpr unsigned OFF_SNAPV = 135168;  // float[2][1024] (8 KB)
static constexpr unsigned OFF_FOLD  = 143360;  // float2[512] fold scratch (4 KB)
static constexpr unsigned OFF_US    = 151552;  // float[64]
static constexpr unsigned OFF_US2   = 151808;  // float[64]  (S2 * u)
static constexpr unsigned OFF_SNAPU = 152064;  // float[2][64]
static constexpr unsigned OFF_RED   = 152576;  // float[16]
static constexpr unsigned OFF_UDL   = 152640;  // float[16]
static constexpr unsigned OFF_MISC  = 152704;  // float[16]
static constexpr unsigned OFF_XN    = 152768;  // float[64]
static constexpr unsigned SMEM_BYTES = 153024; // < 163840 gfx950 LDS

__device__ __forceinline__ void unpack8(const float4 w, float* out) {
    const __half2* h = (const __half2*)&w;
#pragma unroll
    for (int e = 0; e < 4; ++e) {
        float2 f = __half22float2(h[e]);
        out[2 * e]     = f.x;
        out[2 * e + 1] = f.y;
    }
}
__device__ __forceinline__ bool sum_ok(float s) {
    return (s >= 1e-18f) && (s <= 1e18f);   // false for 0/tiny/huge/inf/NaN
}

// exact (m,s) exchange for column tid; used at it==0 and on rare range fallback.
// Uniform per block. Returns new v for column tid.
__device__ __forceinline__ float ms_exchange(
    const __half* __restrict__ Cs, const float* __restrict__ uS2,
    unsigned long long* __restrict__ part, unsigned int* __restrict__ sflag2,
    int p, int b, int s, int it, int tid)
{
    if (tid < 512) {
        const int j0 = tid << 1;
        float m0 = -INFINITY, m1 = -INFINITY;
        for (int r = 0; r < 64; ++r) {
            const float su = uS2[r];
            float2 fc = __half22float2(*(const __half2*)(Cs + (r << 10) + j0));
            m0 = fmaxf(m0, fmaf(fc.x, -S2, su));
            m1 = fmaxf(m1, fmaf(fc.y, -S2, su));
        }
        float t0 = 0.f, t1 = 0.f;
        for (int r = 0; r < 64; ++r) {
            const float su = uS2[r];
            float2 fc = __half22float2(*(const __half2*)(Cs + (r << 10) + j0));
            t0 += exp2f(fmaf(fc.x, -S2, su) - m0);
            t1 += exp2f(fmaf(fc.y, -S2, su) - m1);
        }
        unsigned long long pv0, pv1;
        float2 w0 = make_float2(m0, t0), w1 = make_float2(m1, t1);
        __builtin_memcpy(&pv0, &w0, 8);
        __builtin_memcpy(&pv1, &w1, 8);
        unsigned long long* pb = part + ((((size_t)(p << 4) | b) << 4 | s) << 10);
        __hip_atomic_store(pb + j0,     pv0, __ATOMIC_RELAXED, __HIP_MEMORY_SCOPE_AGENT);
        __hip_atomic_store(pb + j0 + 1, pv1, __ATOMIC_RELAXED, __HIP_MEMORY_SCOPE_AGENT);
    }
    __syncthreads();   // drain part stores
    if (tid == 0)
        __hip_atomic_store(sflag2 + ((((p << 4) | b) << 4 | s) << 4),
                           (unsigned)(it + 1),
                           __ATOMIC_RELEASE, __HIP_MEMORY_SCOPE_AGENT);
    if (tid < 16) {
        while (__hip_atomic_load(sflag2 + ((((p << 4) | b) << 4 | tid) << 4),
                __ATOMIC_ACQUIRE, __HIP_MEMORY_SCOPE_AGENT) < (unsigned)(it + 1))
            __builtin_amdgcn_s_sleep(1);
    }
    __syncthreads();
    // combine 16 slab partials for column tid
    float mv[16], sw[16];
#pragma unroll
    for (int i = 0; i < 16; ++i) {
        unsigned long long pv = __hip_atomic_load(
            part + ((((size_t)(p << 4) | b) << 4 | i) << 10) + tid,
            __ATOMIC_RELAXED, __HIP_MEMORY_SCOPE_AGENT);
        float2 ms;
        __builtin_memcpy(&ms, &pv, 8);
        mv[i] = ms.x; sw[i] = ms.y;
    }
    float M = mv[0];
#pragma unroll
    for (int i = 1; i < 16; ++i) M = fmaxf(M, mv[i]);
    float acc = 0.f;
#pragma unroll
    for (int i = 0; i < 16; ++i) acc = fmaf(sw[i], exp2f(mv[i] - M), acc);
    return UAB - EPSLN2 * (M + log2f(acc));
}

//==================== persistent all-LDS Sinkhorn: one block per (batch, 64-row slab)
// Plain (non-cooperative) launch: 256 blocks @ 1 block/CU are all co-resident;
// inter-block sync is hand-rolled agent-scope flags. Static LDS -> capture-safe.
__global__ __launch_bounds__(1024, 1)
void sinkhorn_lds(const float* __restrict__ x, const float* __restrict__ y,
                  unsigned long long* __restrict__ part,
                  float* __restrict__ udiffg, float* __restrict__ dslot,
                  unsigned int* __restrict__ arriveg,
                  unsigned int* __restrict__ sflag,
                  unsigned int* __restrict__ sflag2,
                  float* __restrict__ dsum,
                  float* __restrict__ out)
{
    __shared__ __align__(16) char smem[SMEM_BYTES];
    __half* Cs    = (__half*)smem;                  // [64][1024] fp16 slab
    float* vS     = (float*)(smem + OFF_VS);
    float* xstage = (float*)(smem + OFF_XST);
    float* snapV  = (float*)(smem + OFF_SNAPV);     // [2][1024]
    float2* fold  = (float2*)(smem + OFF_FOLD);     // [512]
    float* uS     = (float*)(smem + OFF_US);
    float* uS2    = (float*)(smem + OFF_US2);
    float* snapU  = (float*)(smem + OFF_SNAPU);     // [2][64]
    float* red    = (float*)(smem + OFF_RED);
    float* udiffL = (float*)(smem + OFF_UDL);
    float* misc   = (float*)(smem + OFF_MISC);
    float* xnS    = (float*)(smem + OFF_XN);

    const int tid  = threadIdx.x;
    const int lane = tid & 63;
    const int wv   = tid >> 6;
    const int bid  = blockIdx.x;
    // XCD-friendly mapping: batch b's 16 blocks share bid%8
    const int c = bid & 7, kk = bid >> 3;
    const int s = kk & 15;
    const int b = ((kk >> 4) << 3) | c;
    const int rb = wv << 2;                          // wave's 4 rows (phase A)
    // phase-A2 split: all 1024 threads, 2 cols x 32-row half-slab
    const int hh  = tid >> 9;
    const int idx = tid & 511;
    const int j0  = idx << 1;
    const int rlo = hh << 5;

    //---------------- build: stage x slab (64 rows x 64 d), zero u,v
    ((float4*)xstage)[tid] =
        ((const float4*)(x + (((size_t)(b << 10) + (s << 6)) << 6)))[tid];
    vS[tid] = 0.f;
    __syncthreads();
    if (tid < 64) {
        float a = 0.f;
        for (int d = 0; d < 64; d += 4) {
            float4 q = *(const float4*)(xstage + (tid << 6) + d);
            a = fmaf(q.x, q.x, a); a = fmaf(q.y, q.y, a);
            a = fmaf(q.z, q.z, a); a = fmaf(q.w, q.w, a);
        }
        xnS[tid] = a;
        uS[tid] = 0.f;
        uS2[tid] = 0.f;
    }
    __syncthreads();
    // build C slab into LDS: C_ij = |x_i|^2 + |y_j|^2 - 2 x.y
    for (int st = 0; st < 16; ++st) {
        const float* yp = y + (((size_t)(b << 10) + (st << 6) + lane) << 6);
        float acc0 = 0, acc1 = 0, acc2 = 0, acc3 = 0, yn = 0;
        for (int d8 = 0; d8 < 64; d8 += 8) {
            float xv[4][8];
#pragma unroll
            for (int r = 0; r < 4; ++r) {
                float4 A  = *(const float4*)(xstage + ((rb + r) << 6) + d8);
                float4 Bq = *(const float4*)(xstage + ((rb + r) << 6) + d8 + 4);
                xv[r][0] = A.x;  xv[r][1] = A.y;  xv[r][2] = A.z;  xv[r][3] = A.w;
                xv[r][4] = Bq.x; xv[r][5] = Bq.y; xv[r][6] = Bq.z; xv[r][7] = Bq.w;
            }
            float4 ya = *(const float4*)(yp + d8);
            float4 yb = *(const float4*)(yp + d8 + 4);
            float yv[8] = { ya.x, ya.y, ya.z, ya.w, yb.x, yb.y, yb.z, yb.w };
#pragma unroll
            for (int dd = 0; dd < 8; ++dd) {
                const float yd = yv[dd];
                yn   = fmaf(yd, yd, yn);
                acc0 = fmaf(xv[0][dd], yd, acc0);
                acc1 = fmaf(xv[1][dd], yd, acc1);
                acc2 = fmaf(xv[2][dd], yd, acc2);
                acc3 = fmaf(xv[3][dd], yd, acc3);
            }
        }
        const int col = (st << 6) + lane;
        Cs[((rb + 0) << 10) + col] = __float2half(xnS[rb + 0] + yn - 2.f * acc0);
        Cs[((rb + 1) << 10) + col] = __float2half(xnS[rb + 1] + yn - 2.f * acc1);
        Cs[((rb + 2) << 10) + col] = __float2half(xnS[rb + 2] + yn - 2.f * acc2);
        Cs[((rb + 3) << 10) + col] = __float2half(xnS[rb + 3] + yn - 2.f * acc3);
    }
    __syncthreads();   // xstage dead from here; snapV/fold overlay it

    // phase-A lse normalizer guesses (-inf forces exact path at it 0)
    float gRow[4] = { -INFINITY, -INFINITY, -INFINITY, -INFINITY };

    //---------------- Sinkhorn loop (speculative early-stop, lag 2)
    int it = 0;
    bool rolled = false;
    for (; it < MAXIT; ++it) {
        const int p = it & 1;
        // snapshot state-after-(it-1) into ring slot (it-1)&1
        if (it >= 1) {
            snapV[(((it - 1) & 1) << 10) + tid] = vS[tid];
            if (tid < 64) snapU[(((it - 1) & 1) << 6) + tid] = uS[tid];
        }
        // lag-2 verdict check (usually non-blocking)
        if (it >= 2) {
            if (tid == 0) {
                while (__hip_atomic_load(arriveg + ((it - 2) << 4),
                        __ATOMIC_RELAXED, __HIP_MEMORY_SCOPE_AGENT) < 16u)
                    __builtin_amdgcn_s_sleep(2);
                misc[0] = __hip_atomic_load(dslot + ((it - 2) << 4),
                        __ATOMIC_RELAXED, __HIP_MEMORY_SCOPE_AGENT);
            }
            __syncthreads();
            if (misc[0] * 0.0625f < THRESH) {
                vS[tid] = snapV[(((it - 2) & 1) << 10) + tid];
                if (tid < 64) uS[tid] = snapU[(((it - 2) & 1) << 6) + tid];
                __syncthreads();
                rolled = true;
                break;
            }
        }
        //---- phase A: u_i = UAB - eps*lse_j((v_j - C_ij)/eps)  [block-local]
        {
            float sv[16];
            {
                float4 a0 = ((const float4*)vS)[(lane << 1)];
                float4 a1 = ((const float4*)vS)[(lane << 1) + 1];
                float4 a2 = ((const float4*)vS)[128 + (lane << 1)];
                float4 a3 = ((const float4*)vS)[129 + (lane << 1)];
                sv[0] = a0.x * S2; sv[1] = a0.y * S2; sv[2] = a0.z * S2; sv[3] = a0.w * S2;
                sv[4] = a1.x * S2; sv[5] = a1.y * S2; sv[6] = a1.z * S2; sv[7] = a1.w * S2;
                sv[8]  = a2.x * S2; sv[9]  = a2.y * S2; sv[10] = a2.z * S2; sv[11] = a2.w * S2;
                sv[12] = a3.x * S2; sv[13] = a3.y * S2; sv[14] = a3.z * S2; sv[15] = a3.w * S2;
            }
            float4 hA[4], hB[4];
#pragma unroll
            for (int r4 = 0; r4 < 4; ++r4) {
                hA[r4] = ((const float4*)(Cs + ((rb + r4) << 10)))[lane];
                hB[r4] = ((const float4*)(Cs + ((rb + r4) << 10)))[64 + lane];
            }
            float ssr[4];
#pragma unroll
            for (int r4 = 0; r4 < 4; ++r4) {
                float cf[16];
                unpack8(hA[r4], cf); unpack8(hB[r4], cf + 8);
                const float g = gRow[r4];
                float e0 = 0.f, e1 = 0.f, e2 = 0.f, e3 = 0.f;
#pragma unroll
                for (int q = 0; q < 16; q += 4) {
                    e0 += exp2f(fmaf(cf[q + 0], -S2, sv[q + 0]) - g);
                    e1 += exp2f(fmaf(cf[q + 1], -S2, sv[q + 1]) - g);
                    e2 += exp2f(fmaf(cf[q + 2], -S2, sv[q + 2]) - g);
                    e3 += exp2f(fmaf(cf[q + 3], -S2, sv[q + 3]) - g);
                }
                ssr[r4] = (e0 + e1) + (e2 + e3);
            }
#pragma unroll
            for (int off = 32; off; off >>= 1) {
                ssr[0] += __shfl_xor(ssr[0], off, 64);
                ssr[1] += __shfl_xor(ssr[1], off, 64);
                ssr[2] += __shfl_xor(ssr[2], off, 64);
                ssr[3] += __shfl_xor(ssr[3], off, 64);
            }
            float ud4 = 0.f;
#pragma unroll
            for (int r4 = 0; r4 < 4; ++r4) {
                float ss = ssr[r4];
                float gu = gRow[r4];
                if (!sum_ok(ss)) {   // wave-uniform; fires at it 0 only (g=-inf)
                    float cf[16];
                    unpack8(hA[r4], cf); unpack8(hB[r4], cf + 8);
                    float a[16], mx = -INFINITY;
#pragma unroll
                    for (int q = 0; q < 16; ++q) {
                        a[q] = fmaf(cf[q], -S2, sv[q]);
                        mx = fmaxf(mx, a[q]);
                    }
#pragma unroll
                    for (int off = 32; off; off >>= 1)
                        mx = fmaxf(mx, __shfl_xor(mx, off, 64));
                    float e0 = 0.f, e1 = 0.f;
#pragma unroll
                    for (int q = 0; q < 16; q += 2) {
                        e0 += exp2f(a[q]     - mx);
                        e1 += exp2f(a[q + 1] - mx);
                    }
                    ss = e0 + e1;
#pragma unroll
                    for (int off = 32; off; off >>= 1) ss += __shfl_xor(ss, off, 64);
                    gu = mx;
                }
                const float lse = gu + log2f(ss);
                gRow[r4] = lse;
                if (lane == 0) {
                    const int r = rb + r4;
                    const float un = UAB - EPSLN2 * lse;
                    ud4 += fabsf(un - uS[r]);
                    uS[r] = un;
                    uS2[r] = un * S2;
                }
            }
            if (lane == 0) red[wv] = ud4;
        }
        __syncthreads();
        if (tid == 0) {
            float t = 0.f;
#pragma unroll
            for (int g = 0; g < 16; ++g) t += red[g];
            __hip_atomic_store(udiffg + (p << 8) + (b << 4) + s, t,
                               __ATOMIC_RELAXED, __HIP_MEMORY_SCOPE_AGENT);
        }

        float vn;
        if (it == 0) {
            vn = ms_exchange(Cs, uS2, part, sflag2, p, b, s, it, tid);
        } else {
            //---- phase A2 (sum path): shared normalizer = prev column lse
            {
                const float g0 = (UAB - vS[j0])     * S2;
                const float g1 = (UAB - vS[j0 + 1]) * S2;
                float a0 = 0.f, a1 = 0.f, b0a = 0.f, b1a = 0.f;
#pragma unroll
                for (int r = 0; r < 32; r += 2) {
                    float2 fA = __half22float2(
                        *(const __half2*)(Cs + ((rlo + r)     << 10) + j0));
                    float2 fB = __half22float2(
                        *(const __half2*)(Cs + ((rlo + r + 1) << 10) + j0));
                    const float suA = uS2[rlo + r];
                    const float suB = uS2[rlo + r + 1];
                    a0  += exp2f(fmaf(fA.x, -S2, suA) - g0);
                    a1  += exp2f(fmaf(fA.y, -S2, suA) - g1);
                    b0a += exp2f(fmaf(fB.x, -S2, suB) - g0);
                    b1a += exp2f(fmaf(fB.y, -S2, suB) - g1);
                }
                const float s0 = a0 + b0a;
                const float s1 = a1 + b1a;
                if (hh == 1) fold[idx] = make_float2(s0, s1);
                __syncthreads();
                if (hh == 0) {
                    float2 o = fold[idx];
                    float* db = dsum + (((size_t)it << 4 | b) << 10);
                    __hip_atomic_fetch_add(db + j0,     s0 + o.x,
                        __ATOMIC_RELAXED, __HIP_MEMORY_SCOPE_AGENT);
                    __hip_atomic_fetch_add(db + j0 + 1, s1 + o.y,
                        __ATOMIC_RELAXED, __HIP_MEMORY_SCOPE_AGENT);
                }
            }
            __syncthreads();   // drain atomic adds (vmcnt) before flag
            if (tid == 0)
                __hip_atomic_store(sflag + ((((p << 4) | b) << 4 | s) << 4),
                                   (unsigned)(it + 1),
                                   __ATOMIC_RELEASE, __HIP_MEMORY_SCOPE_AGENT);
            if (tid < 16) {
                while (__hip_atomic_load(sflag + ((((p << 4) | b) << 4 | tid) << 4),
                        __ATOMIC_ACQUIRE, __HIP_MEMORY_SCOPE_AGENT) < (unsigned)(it + 1))
                    __builtin_amdgcn_s_sleep(1);
            }
            __syncthreads();
            //---- phase B (sum path): v from totals, uniform range check
            const float total = __hip_atomic_load(
                dsum + (((size_t)it << 4 | b) << 10) + tid,
                __ATOMIC_RELAXED, __HIP_MEMORY_SCOPE_AGENT);
            const float gj = (UAB - vS[tid]) * S2;
            if (tid == 0) misc[1] = 1.f;
            __syncthreads();
            if (!sum_ok(total)) misc[1] = 0.f;
            __syncthreads();
            if (misc[1] != 0.f) {
                vn = UAB - EPSLN2 * (gj + log2f(total));
            } else {
                vn = ms_exchange(Cs, uS2, part, sflag2, p, b, s, it, tid);
            }
        }
        //---- common tail: v write, diff reduce, verdict publish
        {
            float vd = fabsf(vn - vS[tid]);
            vS[tid] = vn;
#pragma unroll
            for (int off = 32; off; off >>= 1) vd += __shfl_xor(vd, off, 64);
            if (lane == 0) red[wv] = vd;
        }
        if (tid < 16 && s == 0)
            udiffL[tid] = __hip_atomic_load(udiffg + (p << 8) + (b << 4) + tid,
                                            __ATOMIC_RELAXED, __HIP_MEMORY_SCOPE_AGENT);
        __syncthreads();
        if (tid == 0 && s == 0) {
            float tot = 0.f;
#pragma unroll
            for (int g = 0; g < 16; ++g) tot += udiffL[g] + red[g];
            __hip_atomic_fetch_add(dslot + (it << 4), tot,
                                   __ATOMIC_RELAXED, __HIP_MEMORY_SCOPE_AGENT);
            __hip_atomic_fetch_add(arriveg + (it << 4), 1u,
                                   __ATOMIC_RELEASE, __HIP_MEMORY_SCOPE_AGENT);
        }
        __syncthreads();
    }

    // reached MAXIT: verdict for MAXIT-2 still unconsumed — may require rollback
    if (!rolled && it == MAXIT) {
        if (tid == 0) {
            while (__hip_atomic_load(arriveg + ((MAXIT - 2) << 4),
                    __ATOMIC_RELAXED, __HIP_MEMORY_SCOPE_AGENT) < 16u)
                __builtin_amdgcn_s_sleep(2);
            misc[0] = __hip_atomic_load(dslot + ((MAXIT - 2) << 4),
                    __ATOMIC_RELAXED, __HIP_MEMORY_SCOPE_AGENT);
        }
        __syncthreads();
        if (misc[0] * 0.0625f < THRESH) {
            vS[tid] = snapV[(((MAXIT - 2) & 1) << 10) + tid];
            if (tid < 64) uS[tid] = snapU[(((MAXIT - 2) & 1) << 6) + tid];
            __syncthreads();
        }
    }

    //---------------- cost: out[b] += sum over slab of exp2(S2(u+v-C))*C
    __syncthreads();
    {
        float sv[16];
        {
            float4 a0 = ((const float4*)vS)[(lane << 1)];
            float4 a1 = ((const float4*)vS)[(lane << 1) + 1];
            float4 a2 = ((const float4*)vS)[128 + (lane << 1)];
            float4 a3 = ((const float4*)vS)[129 + (lane << 1)];
            sv[0] = a0.x * S2; sv[1] = a0.y * S2; sv[2] = a0.z * S2; sv[3] = a0.w * S2;
            sv[4] = a1.x * S2; sv[5] = a1.y * S2; sv[6] = a1.z * S2; sv[7] = a1.w * S2;
            sv[8]  = a2.x * S2; sv[9]  = a2.y * S2; sv[10] = a2.z * S2; sv[11] = a2.w * S2;
            sv[12] = a3.x * S2; sv[13] = a3.y * S2; sv[14] = a3.z * S2; sv[15] = a3.w * S2;
        }
        float acc0 = 0.f, acc1 = 0.f;
#pragma unroll
        for (int r4 = 0; r4 < 4; ++r4) {
            const int r = rb + r4;
            const float su = uS[r] * S2;
            float4 ha = ((const float4*)(Cs + (r << 10)))[lane];
            float4 hb = ((const float4*)(Cs + (r << 10)))[64 + lane];
            float cf[16];
            unpack8(ha, cf); unpack8(hb, cf + 8);
#pragma unroll
            for (int q = 0; q < 16; q += 2) {
                acc0 = fmaf(exp2f(fmaf(cf[q],     -S2, su + sv[q])),     cf[q],     acc0);
                acc1 = fmaf(exp2f(fmaf(cf[q + 1], -S2, su + sv[q + 1])), cf[q + 1], acc1);
            }
        }
        float acc = acc0 + acc1;
#pragma unroll
        for (int off = 32; off; off >>= 1) acc += __shfl_xor(acc, off, 64);
        if (lane == 0) red[wv] = acc;
        __syncthreads();
        if (tid == 0) {
            float t = 0.f;
#pragma unroll
            for (int g = 0; g < 16; ++g) t += red[g];
            atomicAdd(out + b, t);
        }
    }
}

//==================== small init for persistent path: zero counters + out
__global__ __launch_bounds__(256)
void init_small(unsigned int* __restrict__ zb, int nwords, float* __restrict__ out)
{
    const int gt = (blockIdx.x << 8) + threadIdx.x;
    for (int k = gt; k < nwords; k += gridDim.x << 8) zb[k] = 0u;
    if (gt < Bb) out[gt] = 0.f;
}

//==================== ---------- fallback path (round-4 proven) ----------
__global__ __launch_bounds__(256)
void init_kernel(const float* __restrict__ y, float* __restrict__ yT,
                 float* __restrict__ zbase, int zcount4)
{
    __shared__ float sm[64 * 65];
    const int tid = threadIdx.x;
    const int bid = blockIdx.x;
    if (bid < 256) {
        const int b  = bid >> 4;
        const int j0 = (bid & 15) << 6;
        const float4* src = (const float4*)(y + (size_t)(b * Mm + j0) * Dd);
#pragma unroll
        for (int k = 0; k < 4; ++k) {
            const int f4 = tid + (k << 8);
            float4 w = src[f4];
            const int f = f4 << 2;
            float* dst = sm + (f >> 6) * 65 + (f & 63);
            dst[0] = w.x; dst[1] = w.y; dst[2] = w.z; dst[3] = w.w;
        }
        __syncthreads();
        const int jj = tid & 63;
        const int db = tid >> 6;
#pragma unroll
        for (int k = 0; k < 16; ++k) {
            const int d = db + (k << 2);
            yT[(size_t)(b * Dd + d) * Mm + j0 + jj] = sm[jj * 65 + d];
        }
    } else {
        float4* z = (float4*)zbase;
        for (int k = ((bid - 256) << 8) + tid; k < zcount4; k += 65536)
            z[k] = make_float4(0.f, 0.f, 0.f, 0.f);
    }
}

__global__ __launch_bounds__(256)
void cbuild_kernel(const float* __restrict__ x, const float* __restrict__ yT,
                   __half* __restrict__ C, __half* __restrict__ CT)
{
    __shared__ float xs2[2048];
    __shared__ float xn[32];
    __shared__ __align__(16) __half tile[32 * 264];
    const int tid = threadIdx.x;
    const int t   = blockIdx.x;
    const int b   = t >> 7;
    const int rm  = t & 127;
    const int i0  = (rm >> 2) << 5;
    const int j0  = (rm & 3) << 8;
    const float4* xsrc = (const float4*)(x + (size_t)(b * Nn + i0) * Dd);
#pragma unroll
    for (int k = 0; k < 2; ++k) {
        const int f4 = tid + (k << 8);
        float4 w = xsrc[f4];
        float* dst = xs2 + (f4 << 2);
        dst[0] = -2.f * w.x; dst[1] = -2.f * w.y;
        dst[2] = -2.f * w.z; dst[3] = -2.f * w.w;
    }
    __syncthreads();
    if (tid < 32) {
        float a = 0.f;
        for (int d = 0; d < 64; ++d) { float q = xs2[tid * 64 + d]; a = fmaf(q, q, a); }
        xn[tid] = 0.25f * a;
    }
    __syncthreads();
    float acc[32];
#pragma unroll
    for (int ii = 0; ii < 32; ++ii) acc[ii] = 0.f;
    float yn = 0.f;
    const float* yTb = yT + (size_t)b * Dd * Mm + j0 + tid;
    for (int d4 = 0; d4 < 64; d4 += 4) {
        const float y0 = yTb[(size_t)(d4 + 0) * Mm];
        const float y1 = yTb[(size_t)(d4 + 1) * Mm];
        const float y2 = yTb[(size_t)(d4 + 2) * Mm];
        const float y3 = yTb[(size_t)(d4 + 3) * Mm];
        yn = fmaf(y0, y0, yn); yn = fmaf(y1, y1, yn);
        yn = fmaf(y2, y2, yn); yn = fmaf(y3, y3, yn);
#pragma unroll
        for (int ii = 0; ii < 32; ++ii) {
            const float4 xq = *(const float4*)(xs2 + ii * 64 + d4);
            acc[ii] = fmaf(xq.x, y0, acc[ii]);
            acc[ii] = fmaf(xq.y, y1, acc[ii]);
            acc[ii] = fmaf(xq.z, y2, acc[ii]);
            acc[ii] = fmaf(xq.w, y3, acc[ii]);
        }
    }
#pragma unroll
    for (int ii = 0; ii < 32; ++ii) acc[ii] += xn[ii] + yn;
#pragma unroll
    for (int ii = 0; ii < 32; ++ii) tile[ii * 264 + tid] = __float2half(acc[ii]);
    __syncthreads();
#pragma unroll
    for (int p = 0; p < 4; ++p) {
        const int r  = (p << 3) + (tid >> 5);
        const int c8 = (tid & 31) << 3;
        float4 w = *(const float4*)(tile + r * 264 + c8);
        *(float4*)(C + (((size_t)((b << 10) + i0 + r)) << 10) + j0 + c8) = w;
    }
    __half* CTout = CT + ((size_t)((b << 10) + j0 + tid) << 10) + i0;
#pragma unroll
    for (int g = 0; g < 4; ++g) {
        float4 w;
        __half2* hp = (__half2*)&w;
        hp[0] = __floats2half2_rn(acc[8 * g + 0], acc[8 * g + 1]);
        hp[1] = __floats2half2_rn(acc[8 * g + 2], acc[8 * g + 3]);
        hp[2] = __floats2half2_rn(acc[8 * g + 4], acc[8 * g + 5]);
        hp[3] = __floats2half2_rn(acc[8 * g + 6], acc[8 * g + 7]);
        ((float4*)CTout)[g] = w;
    }
}

__global__ __launch_bounds__(256)
void sweep_row(const __half* __restrict__ Cmat, const float* __restrict__ src,
               float* __restrict__ dst, float* __restrict__ dslots, int it)
{
    __shared__ float smw[4];
    const int tid  = threadIdx.x;
    const int lane = tid & 63;
    const int wv   = tid >> 6;
    const int row0 = (blockIdx.x << 3) | (wv << 1);
    const int b    = row0 >> 10;

    if (it > 0) {
        float tv = dslots[((it - 1) << 10) + (lane << 4)];
#pragma unroll
        for (int off = 32; off; off >>= 1) tv += __shfl_xor(tv, off, 64);
        if (tv * (1.f / 16.f) < THRESH) return;
    }

    const float4* s4 = (const float4*)(src + (b << 10));
    float4 sv0 = s4[(lane << 1)];
    float4 sv1 = s4[(lane << 1) + 1];
    float4 sv2 = s4[128 + (lane << 1)];
    float4 sv3 = s4[129 + (lane << 1)];
    float svs[16];
    svs[0] = sv0.x * S2; svs[1] = sv0.y * S2; svs[2] = sv0.z * S2; svs[3] = sv0.w * S2;
    svs[4] = sv1.x * S2; svs[5] = sv1.y * S2; svs[6] = sv1.z * S2; svs[7] = sv1.w * S2;
    svs[8]  = sv2.x * S2; svs[9]  = sv2.y * S2; svs[10] = sv2.z * S2; svs[11] = sv2.w * S2;
    svs[12] = sv3.x * S2; svs[13] = sv3.y * S2; svs[14] = sv3.z * S2; svs[15] = sv3.w * S2;

    const float4* c4 = (const float4*)(Cmat + ((size_t)row0 << 10));
    float4 ca0 = c4[lane];
    float4 ca1 = c4[64 + lane];
    float4 cb0 = c4[128 + lane];
    float4 cb1 = c4[192 + lane];
    float cf[32];
    unpack8(ca0, cf);      unpack8(ca1, cf + 8);
    unpack8(cb0, cf + 16); unpack8(cb1, cf + 24);

    float a0[16], a1[16];
    float m0 = -INFINITY, m1 = -INFINITY;
#pragma unroll
    for (int k = 0; k < 16; ++k) {
        a0[k] = fmaf(cf[k],      -S2, svs[k]);
        a1[k] = fmaf(cf[16 + k], -S2, svs[k]);
        m0 = fmaxf(m0, a0[k]);
        m1 = fmaxf(m1, a1[k]);
    }
#pragma unroll
    for (int off = 32; off; off >>= 1) {
        m0 = fmaxf(m0, __shfl_xor(m0, off, 64));
        m1 = fmaxf(m1, __shfl_xor(m1, off, 64));
    }
    float s0 = 0.f, s1 = 0.f;
#pragma unroll
    for (int k = 0; k < 16; ++k) { s0 += exp2f(a0[k] - m0); s1 += exp2f(a1[k] - m1); }
#pragma unroll
    for (int off = 32; off; off >>= 1) {
        s0 += __shfl_xor(s0, off, 64);
        s1 += __shfl_xor(s1, off, 64);
    }
    if (lane == 0) {
        const float dn0 = UAB - EPSLN2 * (m0 + log2f(s0));
        const float dn1 = UAB - EPSLN2 * (m1 + log2f(s1));
        float* dp = dst + row0;
        const float dd = fabsf(dn0 - dp[0]) + fabsf(dn1 - dp[1]);
        dp[0] = dn0; dp[1] = dn1;
        smw[wv] = dd;
    }
    __syncthreads();
    if (tid == 0) {
        const float bd = smw[0] + smw[1] + smw[2] + smw[3];
        atomicAdd(dslots + (it << 10) + ((blockIdx.x & 63) << 4), bd);
    }
}

__global__ __launch_bounds__(256)
void cost_kernel(const __half* __restrict__ C, const float* __restrict__ u,
                 const float* __restrict__ v, float* __restrict__ cpart)
{
    __shared__ float sm[4];
    const int tid  = threadIdx.x;
    const int lane = tid & 63;
    const int wv   = tid >> 6;
    const int row  = (blockIdx.x << 2) | wv;
    const int b    = row >> 10;
    const float ui = u[row];

    const float4* s4 = (const float4*)(v + (b << 10));
    float4 sv0 = s4[(lane << 1)];
    float4 sv1 = s4[(lane << 1) + 1];
    float4 sv2 = s4[128 + (lane << 1)];
    float4 sv3 = s4[129 + (lane << 1)];
    float vv[16];
    vv[0] = sv0.x; vv[1] = sv0.y; vv[2]  = sv0.z; vv[3]  = sv0.w;
    vv[4] = sv1.x; vv[5] = sv1.y; vv[6]  = sv1.z; vv[7]  = sv1.w;
    vv[8] = sv2.x; vv[9] = sv2.y; vv[10] = sv2.z; vv[11] = sv2.w;
    vv[12] = sv3.x; vv[13] = sv3.y; vv[14] = sv3.z; vv[15] = sv3.w;

    const float4* c4 = (const float4*)(C + ((size_t)row << 10));
    float cf[16];
    unpack8(c4[lane], cf);
    unpack8(c4[64 + lane], cf + 8);

    float acc = 0.f;
#pragma unroll
    for (int k = 0; k < 16; ++k)
        acc = fmaf(exp2f((ui + vv[k] - cf[k]) * S2), cf[k], acc);
#pragma unroll
    for (int off = 32; off; off >>= 1) acc += __shfl_xor(acc, off, 64);
    if (lane == 0) sm[wv] = acc;
    __syncthreads();
    if (tid == 0) cpart[blockIdx.x] = sm[0] + sm[1] + sm[2] + sm[3];
}

__global__ __launch_bounds__(256)
void cost_fin(const float* __restrict__ cpart, float* __restrict__ out)
{
    __shared__ float sm[4];
    const int tid  = threadIdx.x;
    const int lane = tid & 63;
    const int wv   = tid >> 6;
    float vpt = cpart[(blockIdx.x << 8) + tid];
#pragma unroll
    for (int off = 32; off; off >>= 1) vpt += __shfl_xor(vpt, off, 64);
    if (lane == 0) sm[wv] = vpt;
    __syncthreads();
    if (tid == 0) out[blockIdx.x] = sm[0] + sm[1] + sm[2] + sm[3];
}

extern "C" void kernel_launch(void* const* d_in, const int* in_sizes, int n_in,
                              void* d_out, int out_size, void* d_ws, size_t ws_size,
                              hipStream_t stream) {
    const float* x = (const float*)d_in[0];
    const float* y = (const float*)d_in[1];
    float* out = (float*)d_out;

    // ---- fallback region layout (round-4)
    const size_t nCh  = (size_t)Bb * Nn * Mm;
    const size_t nyT  = (size_t)Bb * Dd * Mm;
    const size_t nu   = (size_t)Bb * Nn;
    const size_t nv   = (size_t)Bb * Mm;
    const size_t nds  = (size_t)MAXIT * SLOTS_PER_IT;
    const size_t nbar = 1024;
    const size_t ncp  = 4096;
    const size_t fb_bytes = 2 * nCh * sizeof(__half) +
                            (nyT + nu + nv + nds + nbar + ncp) * sizeof(float);
    __half* C  = (__half*)d_ws;
    __half* CT = C + nCh;
    float*  yT = (float*)(CT + nCh);
    float*  u  = yT + nyT;
    float*  v  = u + nu;
    float*  ds = v + nv;
    float*  cp = ds + nds + nbar;

    // ---- persist-path region (after fallback region, 8B aligned)
    size_t off = (fb_bytes + 7) & ~(size_t)7;
    unsigned long long* part = (unsigned long long*)((char*)d_ws + off);
    off += (size_t)2 * 16 * 16 * 1024 * 8;                 // 4 MB
    float* udiffg = (float*)((char*)d_ws + off);  off += 512 * 4;
    // zero-region start: dslot2, arriveg, sflag, sflag2, dsum contiguous
    float* dslot2 = (float*)((char*)d_ws + off);  off += (size_t)MAXIT * 16 * 4;
    unsigned int* arriveg = (unsigned int*)((char*)d_ws + off); off += (size_t)MAXIT * 16 * 4;
    unsigned int* sflag   = (unsigned int*)((char*)d_ws + off); off += (size_t)2 * 16 * 16 * 16 * 4;
    unsigned int* sflag2  = (unsigned int*)((char*)d_ws + off); off += (size_t)2 * 16 * 16 * 16 * 4;
    float* dsum = (float*)((char*)d_ws + off); off += (size_t)MAXIT * 16 * 1024 * 4;  // 6.55 MB
    const size_t need_bytes = off;
    const int nzwords = MAXIT * 16 + MAXIT * 16 + 2 * (2 * 16 * 16 * 16) +
                        MAXIT * 16 * 1024;

    bool done = false;
    if (ws_size >= need_bytes) {
        hipLaunchKernelGGL(init_small, dim3(256), dim3(256), 0, stream,
                           (unsigned int*)dslot2, nzwords, out);
        // Plain (non-cooperative) launch: static 153 KB LDS, 1 block/CU,
        // 256 blocks == 256 CUs -> all co-resident; graph-capture safe.
        hipLaunchKernelGGL(sinkhorn_lds, dim3(256), dim3(1024), 0, stream,
                           x, y, part, udiffg, dslot2, arriveg, sflag, sflag2,
                           dsum, out);
        done = (hipGetLastError() == hipSuccess);
    }
    if (!done) {
        // round-4 proven fallback chain
        const int zcount4 = (int)((nu + nv + nds + nbar) >> 2);
        hipLaunchKernelGGL(init_kernel, dim3(512), dim3(256), 0, stream,
                           y, yT, u, zcount4);
        hipLaunchKernelGGL(cbuild_kernel, dim3(2048), dim3(256), 0, stream,
                           x, yT, C, CT);
        for (int it = 0; it < MAXIT; ++it) {
            hipLaunchKernelGGL(sweep_row, dim3(2048), dim3(256), 0, stream,
                               C, v, u, ds, it);
            hipLaunchKernelGGL(sweep_row, dim3(2048), dim3(256), 0, stream,
                               CT, u, v, ds, it);
        }
        hipLaunchKernelGGL(cost_kernel, dim3(4096), dim3(256), 0, stream,
                           C, u, v, cp);
        hipLaunchKernelGGL(cost_fin, dim3(16), dim3(256), 0, stream, cp, out);
    }
}

// Round 13
// 1621.358 us; speedup vs baseline: 2.0167x; 2.0167x over previous
//
#include <hip/hip_runtime.h>
#include <hip/hip_fp16.h>
#include <cmath>

static constexpr int   Bb     = 16;
static constexpr int   Nn     = 1024;
static constexpr int   Mm     = 1024;
static constexpr int   Dd     = 64;
static constexpr int   MAXIT  = 100;
static constexpr float THRESH = 1e-4f;
static constexpr float S2     = 144.26950408889634f;   // (1/eps)*log2(e) == 1/(eps*ln2)
static constexpr float EPSLN2 = 0.006931471805599453f; // eps*ln2
static constexpr float UAB    = -0.06931461565651f;    // eps*log(1/1024+1e-8)
static constexpr int SLOTS_PER_IT = 1024;              // fallback dslots stride

// LDS layout for persistent kernel (bytes) — STATIC shared (capture-safe)
static constexpr unsigned OFF_VS    = 131072;  // float[1024]
static constexpr unsigned OFF_XST   = 135168;  // float[4096] build-only; overlaid below
static constexpr unsigned OFF_SNAPV = 135168;  // float[2][1024] (8 KB)
static constexpr unsigned OFF_FOLD  = 143360;  // float2[512] fold scratch (4 KB)
static constexpr unsigned OFF_US    = 151552;  // float[64]
static constexpr unsigned OFF_US2   = 151808;  // float[64]  (S2 * u)
static constexpr unsigned OFF_SNAPU = 152064;  // float[2][64]
static constexpr unsigned OFF_RED   = 152576;  // float[16]
static constexpr unsigned OFF_UDL   = 152640;  // float[16]
static constexpr unsigned OFF_MISC  = 152704;  // float[16]
static constexpr unsigned OFF_XN    = 152768;  // float[64]
static constexpr unsigned SMEM_BYTES = 153024; // < 163840 gfx950 LDS

__device__ __forceinline__ void unpack8(const float4 w, float* out) {
    const __half2* h = (const __half2*)&w;
#pragma unroll
    for (int e = 0; e < 4; ++e) {
        float2 f = __half22float2(h[e]);
        out[2 * e]     = f.x;
        out[2 * e + 1] = f.y;
    }
}
__device__ __forceinline__ bool sum_ok(float s) {
    return (s >= 1e-18f) && (s <= 1e18f);   // false for 0/tiny/huge/inf/NaN
}

// exact (m,s) exchange for column tid; used at it==0 and on rare range fallback.
// Uniform per block. Returns new v for column tid.
__device__ __forceinline__ float ms_exchange(
    const __half* __restrict__ Cs, const float* __restrict__ uS2,
    unsigned long long* __restrict__ part, unsigned int* __restrict__ sflag2,
    int p, int b, int s, int it, int tid)
{
    if (tid < 512) {
        const int j0 = tid << 1;
        float m0 = -INFINITY, m1 = -INFINITY;
        for (int r = 0; r < 64; ++r) {
            const float su = uS2[r];
            float2 fc = __half22float2(*(const __half2*)(Cs + (r << 10) + j0));
            m0 = fmaxf(m0, fmaf(fc.x, -S2, su));
            m1 = fmaxf(m1, fmaf(fc.y, -S2, su));
        }
        float t0 = 0.f, t1 = 0.f;
        for (int r = 0; r < 64; ++r) {
            const float su = uS2[r];
            float2 fc = __half22float2(*(const __half2*)(Cs + (r << 10) + j0));
            t0 += exp2f(fmaf(fc.x, -S2, su) - m0);
            t1 += exp2f(fmaf(fc.y, -S2, su) - m1);
        }
        unsigned long long pv0, pv1;
        float2 w0 = make_float2(m0, t0), w1 = make_float2(m1, t1);
        __builtin_memcpy(&pv0, &w0, 8);
        __builtin_memcpy(&pv1, &w1, 8);
        unsigned long long* pb = part + ((((size_t)(p << 4) | b) << 4 | s) << 10);
        __hip_atomic_store(pb + j0,     pv0, __ATOMIC_RELAXED, __HIP_MEMORY_SCOPE_AGENT);
        __hip_atomic_store(pb + j0 + 1, pv1, __ATOMIC_RELAXED, __HIP_MEMORY_SCOPE_AGENT);
    }
    __syncthreads();   // drain part stores
    if (tid == 0)
        __hip_atomic_store(sflag2 + ((((p << 4) | b) << 4 | s) << 4),
                           (unsigned)(it + 1),
                           __ATOMIC_RELEASE, __HIP_MEMORY_SCOPE_AGENT);
    if (tid < 16) {
        while (__hip_atomic_load(sflag2 + ((((p << 4) | b) << 4 | tid) << 4),
                __ATOMIC_RELAXED, __HIP_MEMORY_SCOPE_AGENT) < (unsigned)(it + 1))
            __builtin_amdgcn_s_sleep(1);
    }
    __syncthreads();
    // combine 16 slab partials for column tid
    float mv[16], sw[16];
#pragma unroll
    for (int i = 0; i < 16; ++i) {
        unsigned long long pv = __hip_atomic_load(
            part + ((((size_t)(p << 4) | b) << 4 | i) << 10) + tid,
            __ATOMIC_RELAXED, __HIP_MEMORY_SCOPE_AGENT);
        float2 ms;
        __builtin_memcpy(&ms, &pv, 8);
        mv[i] = ms.x; sw[i] = ms.y;
    }
    float M = mv[0];
#pragma unroll
    for (int i = 1; i < 16; ++i) M = fmaxf(M, mv[i]);
    float acc = 0.f;
#pragma unroll
    for (int i = 0; i < 16; ++i) acc = fmaf(sw[i], exp2f(mv[i] - M), acc);
    return UAB - EPSLN2 * (M + log2f(acc));
}

//==================== persistent all-LDS Sinkhorn: one block per (batch, 64-row slab)
// Plain (non-cooperative) launch: 256 blocks @ 1 block/CU are all co-resident;
// inter-block sync is hand-rolled agent-scope flags. Static LDS -> capture-safe.
// Body: round-9 form (measured 1.72 ms / 30 MB fetch / 58% VALUBusy) — the
// round-10 ILP rewrite spilled to scratch (2.5 GB fetch) and is reverted.
__global__ __launch_bounds__(1024, 1)
void sinkhorn_lds(const float* __restrict__ x, const float* __restrict__ y,
                  unsigned long long* __restrict__ part,
                  float* __restrict__ udiffg, float* __restrict__ dslot,
                  unsigned int* __restrict__ arriveg,
                  unsigned int* __restrict__ sflag,
                  unsigned int* __restrict__ sflag2,
                  float* __restrict__ dsum,
                  float* __restrict__ out)
{
    __shared__ __align__(16) char smem[SMEM_BYTES];
    __half* Cs    = (__half*)smem;                  // [64][1024] fp16 slab
    float* vS     = (float*)(smem + OFF_VS);
    float* xstage = (float*)(smem + OFF_XST);
    float* snapV  = (float*)(smem + OFF_SNAPV);     // [2][1024]
    float2* fold  = (float2*)(smem + OFF_FOLD);     // [512]
    float* uS     = (float*)(smem + OFF_US);
    float* uS2    = (float*)(smem + OFF_US2);
    float* snapU  = (float*)(smem + OFF_SNAPU);     // [2][64]
    float* red    = (float*)(smem + OFF_RED);
    float* udiffL = (float*)(smem + OFF_UDL);
    float* misc   = (float*)(smem + OFF_MISC);
    float* xnS    = (float*)(smem + OFF_XN);

    const int tid  = threadIdx.x;
    const int lane = tid & 63;
    const int wv   = tid >> 6;
    const int bid  = blockIdx.x;
    // XCD-friendly mapping: batch b's 16 blocks share bid%8
    const int c = bid & 7, kk = bid >> 3;
    const int s = kk & 15;
    const int b = ((kk >> 4) << 3) | c;
    const int rb = wv << 2;                          // wave's 4 rows (phase A)
    // phase-A2 split: all 1024 threads, 2 cols x 32-row half-slab
    const int hh  = tid >> 9;
    const int idx = tid & 511;
    const int j0  = idx << 1;
    const int rlo = hh << 5;

    //---------------- build: stage x slab (64 rows x 64 d), zero u,v
    ((float4*)xstage)[tid] =
        ((const float4*)(x + (((size_t)(b << 10) + (s << 6)) << 6)))[tid];
    vS[tid] = 0.f;
    __syncthreads();
    if (tid < 64) {
        float a = 0.f;
        for (int d = 0; d < 64; d += 4) {
            float4 q = *(const float4*)(xstage + (tid << 6) + d);
            a = fmaf(q.x, q.x, a); a = fmaf(q.y, q.y, a);
            a = fmaf(q.z, q.z, a); a = fmaf(q.w, q.w, a);
        }
        xnS[tid] = a;
        uS[tid] = 0.f;
        uS2[tid] = 0.f;
    }
    __syncthreads();
    // build C slab into LDS: C_ij = |x_i|^2 + |y_j|^2 - 2 x.y
    for (int st = 0; st < 16; ++st) {
        const float* yp = y + (((size_t)(b << 10) + (st << 6) + lane) << 6);
        float acc0 = 0, acc1 = 0, acc2 = 0, acc3 = 0, yn = 0;
        for (int d8 = 0; d8 < 64; d8 += 8) {
            float xv[4][8];
#pragma unroll
            for (int r = 0; r < 4; ++r) {
                float4 A  = *(const float4*)(xstage + ((rb + r) << 6) + d8);
                float4 Bq = *(const float4*)(xstage + ((rb + r) << 6) + d8 + 4);
                xv[r][0] = A.x;  xv[r][1] = A.y;  xv[r][2] = A.z;  xv[r][3] = A.w;
                xv[r][4] = Bq.x; xv[r][5] = Bq.y; xv[r][6] = Bq.z; xv[r][7] = Bq.w;
            }
            float4 ya = *(const float4*)(yp + d8);
            float4 yb = *(const float4*)(yp + d8 + 4);
            float yv[8] = { ya.x, ya.y, ya.z, ya.w, yb.x, yb.y, yb.z, yb.w };
#pragma unroll
            for (int dd = 0; dd < 8; ++dd) {
                const float yd = yv[dd];
                yn   = fmaf(yd, yd, yn);
                acc0 = fmaf(xv[0][dd], yd, acc0);
                acc1 = fmaf(xv[1][dd], yd, acc1);
                acc2 = fmaf(xv[2][dd], yd, acc2);
                acc3 = fmaf(xv[3][dd], yd, acc3);
            }
        }
        const int col = (st << 6) + lane;
        Cs[((rb + 0) << 10) + col] = __float2half(xnS[rb + 0] + yn - 2.f * acc0);
        Cs[((rb + 1) << 10) + col] = __float2half(xnS[rb + 1] + yn - 2.f * acc1);
        Cs[((rb + 2) << 10) + col] = __float2half(xnS[rb + 2] + yn - 2.f * acc2);
        Cs[((rb + 3) << 10) + col] = __float2half(xnS[rb + 3] + yn - 2.f * acc3);
    }
    __syncthreads();   // xstage dead from here; snapV/fold overlay it

    // phase-A lse normalizer guesses (-inf forces exact path at it 0)
    float gRow[4] = { -INFINITY, -INFINITY, -INFINITY, -INFINITY };

    //---------------- Sinkhorn loop (speculative early-stop, lag 2)
    int it = 0;
    bool rolled = false;
    for (; it < MAXIT; ++it) {
        const int p = it & 1;
        // snapshot state-after-(it-1) into ring slot (it-1)&1
        if (it >= 1) {
            snapV[(((it - 1) & 1) << 10) + tid] = vS[tid];
            if (tid < 64) snapU[(((it - 1) & 1) << 6) + tid] = uS[tid];
        }
        // lag-2 verdict check (usually non-blocking)
        if (it >= 2) {
            if (tid == 0) {
                while (__hip_atomic_load(arriveg + ((it - 2) << 4),
                        __ATOMIC_RELAXED, __HIP_MEMORY_SCOPE_AGENT) < 16u)
                    __builtin_amdgcn_s_sleep(2);
                misc[0] = __hip_atomic_load(dslot + ((it - 2) << 4),
                        __ATOMIC_RELAXED, __HIP_MEMORY_SCOPE_AGENT);
            }
            __syncthreads();
            if (misc[0] * 0.0625f < THRESH) {
                vS[tid] = snapV[(((it - 2) & 1) << 10) + tid];
                if (tid < 64) uS[tid] = snapU[(((it - 2) & 1) << 6) + tid];
                __syncthreads();
                rolled = true;
                break;
            }
        }
        //---- phase A: u_i = UAB - eps*lse_j((v_j - C_ij)/eps)  [block-local]
        {
            float sv[16];
            {
                float4 a0 = ((const float4*)vS)[(lane << 1)];
                float4 a1 = ((const float4*)vS)[(lane << 1) + 1];
                float4 a2 = ((const float4*)vS)[128 + (lane << 1)];
                float4 a3 = ((const float4*)vS)[129 + (lane << 1)];
                sv[0] = a0.x * S2; sv[1] = a0.y * S2; sv[2] = a0.z * S2; sv[3] = a0.w * S2;
                sv[4] = a1.x * S2; sv[5] = a1.y * S2; sv[6] = a1.z * S2; sv[7] = a1.w * S2;
                sv[8]  = a2.x * S2; sv[9]  = a2.y * S2; sv[10] = a2.z * S2; sv[11] = a2.w * S2;
                sv[12] = a3.x * S2; sv[13] = a3.y * S2; sv[14] = a3.z * S2; sv[15] = a3.w * S2;
            }
            float ud4 = 0.f;
#pragma unroll
            for (int r4 = 0; r4 < 4; ++r4) {
                const int r = rb + r4;
                float4 ha = ((const float4*)(Cs + (r << 10)))[lane];
                float4 hb = ((const float4*)(Cs + (r << 10)))[64 + lane];
                float cf[16];
                unpack8(ha, cf); unpack8(hb, cf + 8);
                float a[16];
                const float g = gRow[r4];
                float ss = 0.f;
#pragma unroll
                for (int q = 0; q < 16; ++q) {
                    a[q] = fmaf(cf[q], -S2, sv[q]);
                    ss += exp2f(a[q] - g);
                }
#pragma unroll
                for (int off = 32; off; off >>= 1) ss += __shfl_xor(ss, off, 64);
                float gu = g;
                if (!sum_ok(ss)) {   // wave-uniform; fires at it 0 only (g=-inf)
                    float mx = a[0];
#pragma unroll
                    for (int q = 1; q < 16; ++q) mx = fmaxf(mx, a[q]);
#pragma unroll
                    for (int off = 32; off; off >>= 1)
                        mx = fmaxf(mx, __shfl_xor(mx, off, 64));
                    ss = 0.f;
#pragma unroll
                    for (int q = 0; q < 16; ++q) ss += exp2f(a[q] - mx);
#pragma unroll
                    for (int off = 32; off; off >>= 1) ss += __shfl_xor(ss, off, 64);
                    gu = mx;
                }
                const float lse = gu + log2f(ss);   // uniform across wave
                gRow[r4] = lse;                     // next iteration's guess
                if (lane == 0) {
                    const float un = UAB - EPSLN2 * lse;
                    ud4 += fabsf(un - uS[r]);
                    uS[r] = un;
                    uS2[r] = un * S2;
                }
            }
            if (lane == 0) red[wv] = ud4;
        }
        __syncthreads();
        if (tid == 0) {
            float t = 0.f;
#pragma unroll
            for (int g = 0; g < 16; ++g) t += red[g];
            __hip_atomic_store(udiffg + (p << 8) + (b << 4) + s, t,
                               __ATOMIC_RELAXED, __HIP_MEMORY_SCOPE_AGENT);
        }

        float vn;
        if (it == 0) {
            vn = ms_exchange(Cs, uS2, part, sflag2, p, b, s, it, tid);
        } else {
            //---- phase A2 (sum path): shared normalizer = prev column lse
            {
                const float g0 = (UAB - vS[j0])     * S2;
                const float g1 = (UAB - vS[j0 + 1]) * S2;
                float s0 = 0.f, s1 = 0.f;
                for (int r = rlo; r < rlo + 32; ++r) {
                    const float su = uS2[r];
                    float2 fc = __half22float2(*(const __half2*)(Cs + (r << 10) + j0));
                    s0 += exp2f(fmaf(fc.x, -S2, su) - g0);
                    s1 += exp2f(fmaf(fc.y, -S2, su) - g1);
                }
                if (hh == 1) fold[idx] = make_float2(s0, s1);
                __syncthreads();
                if (hh == 0) {
                    float2 o = fold[idx];
                    float* db = dsum + (((size_t)it << 4 | b) << 10);
                    __hip_atomic_fetch_add(db + j0,     s0 + o.x,
                        __ATOMIC_RELAXED, __HIP_MEMORY_SCOPE_AGENT);
                    __hip_atomic_fetch_add(db + j0 + 1, s1 + o.y,
                        __ATOMIC_RELAXED, __HIP_MEMORY_SCOPE_AGENT);
                }
            }
            __syncthreads();   // drain atomic adds (vmcnt) before flag
            if (tid == 0)
                __hip_atomic_store(sflag + ((((p << 4) | b) << 4 | s) << 4),
                                   (unsigned)(it + 1),
                                   __ATOMIC_RELEASE, __HIP_MEMORY_SCOPE_AGENT);
            if (tid < 16) {
                while (__hip_atomic_load(sflag + ((((p << 4) | b) << 4 | tid) << 4),
                        __ATOMIC_RELAXED, __HIP_MEMORY_SCOPE_AGENT) < (unsigned)(it + 1))
                    __builtin_amdgcn_s_sleep(1);
            }
            __syncthreads();
            //---- phase B (sum path): v from totals, uniform range check
            const float total = __hip_atomic_load(
                dsum + (((size_t)it << 4 | b) << 10) + tid,
                __ATOMIC_RELAXED, __HIP_MEMORY_SCOPE_AGENT);
            const float gj = (UAB - vS[tid]) * S2;
            if (tid == 0) misc[1] = 1.f;
            __syncthreads();
            if (!sum_ok(total)) misc[1] = 0.f;
            __syncthreads();
            if (misc[1] != 0.f) {
                vn = UAB - EPSLN2 * (gj + log2f(total));
            } else {
                vn = ms_exchange(Cs, uS2, part, sflag2, p, b, s, it, tid);
            }
        }
        //---- common tail: v write, diff reduce, verdict publish
        {
            float vd = fabsf(vn - vS[tid]);
            vS[tid] = vn;
#pragma unroll
            for (int off = 32; off; off >>= 1) vd += __shfl_xor(vd, off, 64);
            if (lane == 0) red[wv] = vd;
        }
        if (tid < 16 && s == 0)
            udiffL[tid] = __hip_atomic_load(udiffg + (p << 8) + (b << 4) + tid,
                                            __ATOMIC_RELAXED, __HIP_MEMORY_SCOPE_AGENT);
        __syncthreads();
        if (tid == 0 && s == 0) {
            float tot = 0.f;
#pragma unroll
            for (int g = 0; g < 16; ++g) tot += udiffL[g] + red[g];
            __hip_atomic_fetch_add(dslot + (it << 4), tot,
                                   __ATOMIC_RELAXED, __HIP_MEMORY_SCOPE_AGENT);
            __hip_atomic_fetch_add(arriveg + (it << 4), 1u,
                                   __ATOMIC_RELEASE, __HIP_MEMORY_SCOPE_AGENT);
        }
        __syncthreads();
    }

    // reached MAXIT: verdict for MAXIT-2 still unconsumed — may require rollback
    if (!rolled && it == MAXIT) {
        if (tid == 0) {
            while (__hip_atomic_load(arriveg + ((MAXIT - 2) << 4),
                    __ATOMIC_RELAXED, __HIP_MEMORY_SCOPE_AGENT) < 16u)
                __builtin_amdgcn_s_sleep(2);
            misc[0] = __hip_atomic_load(dslot + ((MAXIT - 2) << 4),
                    __ATOMIC_RELAXED, __HIP_MEMORY_SCOPE_AGENT);
        }
        __syncthreads();
        if (misc[0] * 0.0625f < THRESH) {
            vS[tid] = snapV[(((MAXIT - 2) & 1) << 10) + tid];
            if (tid < 64) uS[tid] = snapU[(((MAXIT - 2) & 1) << 6) + tid];
            __syncthreads();
        }
    }

    //---------------- cost: out[b] += sum over slab of exp2(S2(u+v-C))*C
    __syncthreads();
    {
        float sv[16];
        {
            float4 a0 = ((const float4*)vS)[(lane << 1)];
            float4 a1 = ((const float4*)vS)[(lane << 1) + 1];
            float4 a2 = ((const float4*)vS)[128 + (lane << 1)];
            float4 a3 = ((const float4*)vS)[129 + (lane << 1)];
            sv[0] = a0.x * S2; sv[1] = a0.y * S2; sv[2] = a0.z * S2; sv[3] = a0.w * S2;
            sv[4] = a1.x * S2; sv[5] = a1.y * S2; sv[6] = a1.z * S2; sv[7] = a1.w * S2;
            sv[8]  = a2.x * S2; sv[9]  = a2.y * S2; sv[10] = a2.z * S2; sv[11] = a2.w * S2;
            sv[12] = a3.x * S2; sv[13] = a3.y * S2; sv[14] = a3.z * S2; sv[15] = a3.w * S2;
        }
        float acc = 0.f;
#pragma unroll
        for (int r4 = 0; r4 < 4; ++r4) {
            const int r = rb + r4;
            const float su = uS[r] * S2;
            float4 ha = ((const float4*)(Cs + (r << 10)))[lane];
            float4 hb = ((const float4*)(Cs + (r << 10)))[64 + lane];
            float cf[16];
            unpack8(ha, cf); unpack8(hb, cf + 8);
#pragma unroll
            for (int q = 0; q < 16; ++q)
                acc = fmaf(exp2f(fmaf(cf[q], -S2, su + sv[q])), cf[q], acc);
        }
#pragma unroll
        for (int off = 32; off; off >>= 1) acc += __shfl_xor(acc, off, 64);
        if (lane == 0) red[wv] = acc;
        __syncthreads();
        if (tid == 0) {
            float t = 0.f;
#pragma unroll
            for (int g = 0; g < 16; ++g) t += red[g];
            atomicAdd(out + b, t);
        }
    }
}

//==================== small init for persistent path: zero counters + out
__global__ __launch_bounds__(256)
void init_small(unsigned int* __restrict__ zb, int nwords, float* __restrict__ out)
{
    const int gt = (blockIdx.x << 8) + threadIdx.x;
    for (int k = gt; k < nwords; k += gridDim.x << 8) zb[k] = 0u;
    if (gt < Bb) out[gt] = 0.f;
}

//==================== ---------- fallback path (round-4 proven) ----------
__global__ __launch_bounds__(256)
void init_kernel(const float* __restrict__ y, float* __restrict__ yT,
                 float* __restrict__ zbase, int zcount4)
{
    __shared__ float sm[64 * 65];
    const int tid = threadIdx.x;
    const int bid = blockIdx.x;
    if (bid < 256) {
        const int b  = bid >> 4;
        const int j0 = (bid & 15) << 6;
        const float4* src = (const float4*)(y + (size_t)(b * Mm + j0) * Dd);
#pragma unroll
        for (int k = 0; k < 4; ++k) {
            const int f4 = tid + (k << 8);
            float4 w = src[f4];
            const int f = f4 << 2;
            float* dst = sm + (f >> 6) * 65 + (f & 63);
            dst[0] = w.x; dst[1] = w.y; dst[2] = w.z; dst[3] = w.w;
        }
        __syncthreads();
        const int jj = tid & 63;
        const int db = tid >> 6;
#pragma unroll
        for (int k = 0; k < 16; ++k) {
            const int d = db + (k << 2);
            yT[(size_t)(b * Dd + d) * Mm + j0 + jj] = sm[jj * 65 + d];
        }
    } else {
        float4* z = (float4*)zbase;
        for (int k = ((bid - 256) << 8) + tid; k < zcount4; k += 65536)
            z[k] = make_float4(0.f, 0.f, 0.f, 0.f);
    }
}

__global__ __launch_bounds__(256)
void cbuild_kernel(const float* __restrict__ x, const float* __restrict__ yT,
                   __half* __restrict__ C, __half* __restrict__ CT)
{
    __shared__ float xs2[2048];
    __shared__ float xn[32];
    __shared__ __align__(16) __half tile[32 * 264];
    const int tid = threadIdx.x;
    const int t   = blockIdx.x;
    const int b   = t >> 7;
    const int rm  = t & 127;
    const int i0  = (rm >> 2) << 5;
    const int j0  = (rm & 3) << 8;
    const float4* xsrc = (const float4*)(x + (size_t)(b * Nn + i0) * Dd);
#pragma unroll
    for (int k = 0; k < 2; ++k) {
        const int f4 = tid + (k << 8);
        float4 w = xsrc[f4];
        float* dst = xs2 + (f4 << 2);
        dst[0] = -2.f * w.x; dst[1] = -2.f * w.y;
        dst[2] = -2.f * w.z; dst[3] = -2.f * w.w;
    }
    __syncthreads();
    if (tid < 32) {
        float a = 0.f;
        for (int d = 0; d < 64; ++d) { float q = xs2[tid * 64 + d]; a = fmaf(q, q, a); }
        xn[tid] = 0.25f * a;
    }
    __syncthreads();
    float acc[32];
#pragma unroll
    for (int ii = 0; ii < 32; ++ii) acc[ii] = 0.f;
    float yn = 0.f;
    const float* yTb = yT + (size_t)b * Dd * Mm + j0 + tid;
    for (int d4 = 0; d4 < 64; d4 += 4) {
        const float y0 = yTb[(size_t)(d4 + 0) * Mm];
        const float y1 = yTb[(size_t)(d4 + 1) * Mm];
        const float y2 = yTb[(size_t)(d4 + 2) * Mm];
        const float y3 = yTb[(size_t)(d4 + 3) * Mm];
        yn = fmaf(y0, y0, yn); yn = fmaf(y1, y1, yn);
        yn = fmaf(y2, y2, yn); yn = fmaf(y3, y3, yn);
#pragma unroll
        for (int ii = 0; ii < 32; ++ii) {
            const float4 xq = *(const float4*)(xs2 + ii * 64 + d4);
            acc[ii] = fmaf(xq.x, y0, acc[ii]);
            acc[ii] = fmaf(xq.y, y1, acc[ii]);
            acc[ii] = fmaf(xq.z, y2, acc[ii]);
            acc[ii] = fmaf(xq.w, y3, acc[ii]);
        }
    }
#pragma unroll
    for (int ii = 0; ii < 32; ++ii) acc[ii] += xn[ii] + yn;
#pragma unroll
    for (int ii = 0; ii < 32; ++ii) tile[ii * 264 + tid] = __float2half(acc[ii]);
    __syncthreads();
#pragma unroll
    for (int p = 0; p < 4; ++p) {
        const int r  = (p << 3) + (tid >> 5);
        const int c8 = (tid & 31) << 3;
        float4 w = *(const float4*)(tile + r * 264 + c8);
        *(float4*)(C + (((size_t)((b << 10) + i0 + r)) << 10) + j0 + c8) = w;
    }
    __half* CTout = CT + ((size_t)((b << 10) + j0 + tid) << 10) + i0;
#pragma unroll
    for (int g = 0; g < 4; ++g) {
        float4 w;
        __half2* hp = (__half2*)&w;
        hp[0] = __floats2half2_rn(acc[8 * g + 0], acc[8 * g + 1]);
        hp[1] = __floats2half2_rn(acc[8 * g + 2], acc[8 * g + 3]);
        hp[2] = __floats2half2_rn(acc[8 * g + 4], acc[8 * g + 5]);
        hp[3] = __floats2half2_rn(acc[8 * g + 6], acc[8 * g + 7]);
        ((float4*)CTout)[g] = w;
    }
}

__global__ __launch_bounds__(256)
void sweep_row(const __half* __restrict__ Cmat, const float* __restrict__ src,
               float* __restrict__ dst, float* __restrict__ dslots, int it)
{
    __shared__ float smw[4];
    const int tid  = threadIdx.x;
    const int lane = tid & 63;
    const int wv   = tid >> 6;
    const int row0 = (blockIdx.x << 3) | (wv << 1);
    const int b    = row0 >> 10;

    if (it > 0) {
        float tv = dslots[((it - 1) << 10) + (lane << 4)];
#pragma unroll
        for (int off = 32; off; off >>= 1) tv += __shfl_xor(tv, off, 64);
        if (tv * (1.f / 16.f) < THRESH) return;
    }

    const float4* s4 = (const float4*)(src + (b << 10));
    float4 sv0 = s4[(lane << 1)];
    float4 sv1 = s4[(lane << 1) + 1];
    float4 sv2 = s4[128 + (lane << 1)];
    float4 sv3 = s4[129 + (lane << 1)];
    float svs[16];
    svs[0] = sv0.x * S2; svs[1] = sv0.y * S2; svs[2] = sv0.z * S2; svs[3] = sv0.w * S2;
    svs[4] = sv1.x * S2; svs[5] = sv1.y * S2; svs[6] = sv1.z * S2; svs[7] = sv1.w * S2;
    svs[8]  = sv2.x * S2; svs[9]  = sv2.y * S2; svs[10] = sv2.z * S2; svs[11] = sv2.w * S2;
    svs[12] = sv3.x * S2; svs[13] = sv3.y * S2; svs[14] = sv3.z * S2; svs[15] = sv3.w * S2;

    const float4* c4 = (const float4*)(Cmat + ((size_t)row0 << 10));
    float4 ca0 = c4[lane];
    float4 ca1 = c4[64 + lane];
    float4 cb0 = c4[128 + lane];
    float4 cb1 = c4[192 + lane];
    float cf[32];
    unpack8(ca0, cf);      unpack8(ca1, cf + 8);
    unpack8(cb0, cf + 16); unpack8(cb1, cf + 24);

    float a0[16], a1[16];
    float m0 = -INFINITY, m1 = -INFINITY;
#pragma unroll
    for (int k = 0; k < 16; ++k) {
        a0[k] = fmaf(cf[k],      -S2, svs[k]);
        a1[k] = fmaf(cf[16 + k], -S2, svs[k]);
        m0 = fmaxf(m0, a0[k]);
        m1 = fmaxf(m1, a1[k]);
    }
#pragma unroll
    for (int off = 32; off; off >>= 1) {
        m0 = fmaxf(m0, __shfl_xor(m0, off, 64));
        m1 = fmaxf(m1, __shfl_xor(m1, off, 64));
    }
    float s0 = 0.f, s1 = 0.f;
#pragma unroll
    for (int k = 0; k < 16; ++k) { s0 += exp2f(a0[k] - m0); s1 += exp2f(a1[k] - m1); }
#pragma unroll
    for (int off = 32; off; off >>= 1) {
        s0 += __shfl_xor(s0, off, 64);
        s1 += __shfl_xor(s1, off, 64);
    }
    if (lane == 0) {
        const float dn0 = UAB - EPSLN2 * (m0 + log2f(s0));
        const float dn1 = UAB - EPSLN2 * (m1 + log2f(s1));
        float* dp = dst + row0;
        const float dd = fabsf(dn0 - dp[0]) + fabsf(dn1 - dp[1]);
        dp[0] = dn0; dp[1] = dn1;
        smw[wv] = dd;
    }
    __syncthreads();
    if (tid == 0) {
        const float bd = smw[0] + smw[1] + smw[2] + smw[3];
        atomicAdd(dslots + (it << 10) + ((blockIdx.x & 63) << 4), bd);
    }
}

__global__ __launch_bounds__(256)
void cost_kernel(const __half* __restrict__ C, const float* __restrict__ u,
                 const float* __restrict__ v, float* __restrict__ cpart)
{
    __shared__ float sm[4];
    const int tid  = threadIdx.x;
    const int lane = tid & 63;
    const int wv   = tid >> 6;
    const int row  = (blockIdx.x << 2) | wv;
    const int b    = row >> 10;
    const float ui = u[row];

    const float4* s4 = (const float4*)(v + (b << 10));
    float4 sv0 = s4[(lane << 1)];
    float4 sv1 = s4[(lane << 1) + 1];
    float4 sv2 = s4[128 + (lane << 1)];
    float4 sv3 = s4[129 + (lane << 1)];
    float vv[16];
    vv[0] = sv0.x; vv[1] = sv0.y; vv[2]  = sv0.z; vv[3]  = sv0.w;
    vv[4] = sv1.x; vv[5] = sv1.y; vv[6]  = sv1.z; vv[7]  = sv1.w;
    vv[8] = sv2.x; vv[9] = sv2.y; vv[10] = sv2.z; vv[11] = sv2.w;
    vv[12] = sv3.x; vv[13] = sv3.y; vv[14] = sv3.z; vv[15] = sv3.w;

    const float4* c4 = (const float4*)(C + ((size_t)row << 10));
    float cf[16];
    unpack8(c4[lane], cf);
    unpack8(c4[64 + lane], cf + 8);

    float acc = 0.f;
#pragma unroll
    for (int k = 0; k < 16; ++k)
        acc = fmaf(exp2f((ui + vv[k] - cf[k]) * S2), cf[k], acc);
#pragma unroll
    for (int off = 32; off; off >>= 1) acc += __shfl_xor(acc, off, 64);
    if (lane == 0) sm[wv] = acc;
    __syncthreads();
    if (tid == 0) cpart[blockIdx.x] = sm[0] + sm[1] + sm[2] + sm[3];
}

__global__ __launch_bounds__(256)
void cost_fin(const float* __restrict__ cpart, float* __restrict__ out)
{
    __shared__ float sm[4];
    const int tid  = threadIdx.x;
    const int lane = tid & 63;
    const int wv   = tid >> 6;
    float vpt = cpart[(blockIdx.x << 8) + tid];
#pragma unroll
    for (int off = 32; off; off >>= 1) vpt += __shfl_xor(vpt, off, 64);
    if (lane == 0) sm[wv] = vpt;
    __syncthreads();
    if (tid == 0) out[blockIdx.x] = sm[0] + sm[1] + sm[2] + sm[3];
}

extern "C" void kernel_launch(void* const* d_in, const int* in_sizes, int n_in,
                              void* d_out, int out_size, void* d_ws, size_t ws_size,
                              hipStream_t stream) {
    const float* x = (const float*)d_in[0];
    const float* y = (const float*)d_in[1];
    float* out = (float*)d_out;

    // ---- fallback region layout (round-4)
    const size_t nCh  = (size_t)Bb * Nn * Mm;
    const size_t nyT  = (size_t)Bb * Dd * Mm;
    const size_t nu   = (size_t)Bb * Nn;
    const size_t nv   = (size_t)Bb * Mm;
    const size_t nds  = (size_t)MAXIT * SLOTS_PER_IT;
    const size_t nbar = 1024;
    const size_t ncp  = 4096;
    const size_t fb_bytes = 2 * nCh * sizeof(__half) +
                            (nyT + nu + nv + nds + nbar + ncp) * sizeof(float);
    __half* C  = (__half*)d_ws;
    __half* CT = C + nCh;
    float*  yT = (float*)(CT + nCh);
    float*  u  = yT + nyT;
    float*  v  = u + nu;
    float*  ds = v + nv;
    float*  cp = ds + nds + nbar;

    // ---- persist-path region (after fallback region, 8B aligned)
    size_t off = (fb_bytes + 7) & ~(size_t)7;
    unsigned long long* part = (unsigned long long*)((char*)d_ws + off);
    off += (size_t)2 * 16 * 16 * 1024 * 8;                 // 4 MB
    float* udiffg = (float*)((char*)d_ws + off);  off += 512 * 4;
    // zero-region start: dslot2, arriveg, sflag, sflag2, dsum contiguous
    float* dslot2 = (float*)((char*)d_ws + off);  off += (size_t)MAXIT * 16 * 4;
    unsigned int* arriveg = (unsigned int*)((char*)d_ws + off); off += (size_t)MAXIT * 16 * 4;
    unsigned int* sflag   = (unsigned int*)((char*)d_ws + off); off += (size_t)2 * 16 * 16 * 16 * 4;
    unsigned int* sflag2  = (unsigned int*)((char*)d_ws + off); off += (size_t)2 * 16 * 16 * 16 * 4;
    float* dsum = (float*)((char*)d_ws + off); off += (size_t)MAXIT * 16 * 1024 * 4;  // 6.55 MB
    const size_t need_bytes = off;
    const int nzwords = MAXIT * 16 + MAXIT * 16 + 2 * (2 * 16 * 16 * 16) +
                        MAXIT * 16 * 1024;

    bool done = false;
    if (ws_size >= need_bytes) {
        hipLaunchKernelGGL(init_small, dim3(256), dim3(256), 0, stream,
                           (unsigned int*)dslot2, nzwords, out);
        // Plain (non-cooperative) launch: static 153 KB LDS, 1 block/CU,
        // 256 blocks == 256 CUs -> all co-resident; graph-capture safe.
        hipLaunchKernelGGL(sinkhorn_lds, dim3(256), dim3(1024), 0, stream,
                           x, y, part, udiffg, dslot2, arriveg, sflag, sflag2,
                           dsum, out);
        done = (hipGetLastError() == hipSuccess);
    }
    if (!done) {
        // round-4 proven fallback chain
        const int zcount4 = (int)((nu + nv + nds + nbar) >> 2);
        hipLaunchKernelGGL(init_kernel, dim3(512), dim3(256), 0, stream,
                           y, yT, u, zcount4);
        hipLaunchKernelGGL(cbuild_kernel, dim3(2048), dim3(256), 0, stream,
                           x, yT, C, CT);
        for (int it = 0; it < MAXIT; ++it) {
            hipLaunchKernelGGL(sweep_row, dim3(2048), dim3(256), 0, stream,
                               C, v, u, ds, it);
            hipLaunchKernelGGL(sweep_row, dim3(2048), dim3(256), 0, stream,
                               CT, u, v, ds, it);
        }
        hipLaunchKernelGGL(cost_kernel, dim3(4096), dim3(256), 0, stream,
                           C, u, v, cp);
        hipLaunchKernelGGL(cost_fin, dim3(16), dim3(256), 0, stream, cp, out);
    }
}

// Round 14
// 1268.375 us; speedup vs baseline: 2.5779x; 1.2783x over previous
//
#include <hip/hip_runtime.h>
#include <hip/hip_fp16.h>
#include <cmath>

static constexpr int   Bb     = 16;
static constexpr int   Nn     = 1024;
static constexpr int   Mm     = 1024;
static constexpr int   Dd     = 64;
static constexpr int   MAXIT  = 100;
static constexpr float THRESH = 1e-4f;
static constexpr float S2     = 144.26950408889634f;   // (1/eps)*log2(e) == 1/(eps*ln2)
static constexpr float EPSLN2 = 0.006931471805599453f; // eps*ln2
static constexpr float UAB    = -0.06931461565651f;    // eps*log(1/1024+1e-8)
static constexpr int SLOTS_PER_IT = 1024;              // fallback dslots stride

// LDS layout for persistent kernel (bytes) — STATIC shared (capture-safe)
static constexpr unsigned OFF_VS    = 131072;  // float[1024]
static constexpr unsigned OFF_XST   = 135168;  // float[4096] build-only; overlaid below
static constexpr unsigned OFF_SNAPV = 135168;  // float[2][1024] (8 KB)
static constexpr unsigned OFF_FOLD  = 143360;  // float2[512] fold scratch (4 KB)
static constexpr unsigned OFF_US    = 151552;  // float[64]
static constexpr unsigned OFF_US2   = 151808;  // float[64]  (S2 * u)
static constexpr unsigned OFF_SNAPU = 152064;  // float[2][64]
static constexpr unsigned OFF_RED   = 152576;  // float[16]
static constexpr unsigned OFF_UDL   = 152640;  // float[16]
static constexpr unsigned OFF_MISC  = 152704;  // float[16]
static constexpr unsigned OFF_XN    = 152768;  // float[64]
static constexpr unsigned SMEM_BYTES = 153024; // < 163840 gfx950 LDS

// Raw transcendental instructions (1 inst each, no libm denormal fixup).
// Safe here: Gibbs sums are guarded by sum_ok (exact redo on overflow);
// flushed tiny terms are negligible in sums ~1.
__device__ __forceinline__ float fexp2(float x) { return __builtin_amdgcn_exp2f(x); }
__device__ __forceinline__ float flog2(float x) { return __builtin_amdgcn_logf(x); }

__device__ __forceinline__ void unpack8(const float4 w, float* out) {
    const __half2* h = (const __half2*)&w;
#pragma unroll
    for (int e = 0; e < 4; ++e) {
        float2 f = __half22float2(h[e]);
        out[2 * e]     = f.x;
        out[2 * e + 1] = f.y;
    }
}
__device__ __forceinline__ bool sum_ok(float s) {
    return (s >= 1e-18f) && (s <= 1e18f);   // false for 0/tiny/huge/inf/NaN
}

// exact (m,s) exchange for column tid; used at it==0 and on rare range fallback.
// Uniform per block. Returns new v for column tid.
__device__ __forceinline__ float ms_exchange(
    const __half* __restrict__ Cs, const float* __restrict__ uS2,
    unsigned long long* __restrict__ part, unsigned int* __restrict__ sflag2,
    int p, int b, int s, int it, int tid)
{
    if (tid < 512) {
        const int j0 = tid << 1;
        float m0 = -INFINITY, m1 = -INFINITY;
        for (int r = 0; r < 64; ++r) {
            const float su = uS2[r];
            float2 fc = __half22float2(*(const __half2*)(Cs + (r << 10) + j0));
            m0 = fmaxf(m0, fmaf(fc.x, -S2, su));
            m1 = fmaxf(m1, fmaf(fc.y, -S2, su));
        }
        float t0 = 0.f, t1 = 0.f;
        for (int r = 0; r < 64; ++r) {
            const float su = uS2[r];
            float2 fc = __half22float2(*(const __half2*)(Cs + (r << 10) + j0));
            t0 += fexp2(fmaf(fc.x, -S2, su) - m0);
            t1 += fexp2(fmaf(fc.y, -S2, su) - m1);
        }
        unsigned long long pv0, pv1;
        float2 w0 = make_float2(m0, t0), w1 = make_float2(m1, t1);
        __builtin_memcpy(&pv0, &w0, 8);
        __builtin_memcpy(&pv1, &w1, 8);
        unsigned long long* pb = part + ((((size_t)(p << 4) | b) << 4 | s) << 10);
        __hip_atomic_store(pb + j0,     pv0, __ATOMIC_RELAXED, __HIP_MEMORY_SCOPE_AGENT);
        __hip_atomic_store(pb + j0 + 1, pv1, __ATOMIC_RELAXED, __HIP_MEMORY_SCOPE_AGENT);
    }
    __syncthreads();   // drain part stores
    if (tid == 0)
        __hip_atomic_store(sflag2 + ((((p << 4) | b) << 4 | s) << 4),
                           (unsigned)(it + 1),
                           __ATOMIC_RELEASE, __HIP_MEMORY_SCOPE_AGENT);
    if (tid < 16) {
        while (__hip_atomic_load(sflag2 + ((((p << 4) | b) << 4 | tid) << 4),
                __ATOMIC_RELAXED, __HIP_MEMORY_SCOPE_AGENT) < (unsigned)(it + 1))
            __builtin_amdgcn_s_sleep(1);
    }
    __syncthreads();
    // combine 16 slab partials for column tid
    float mv[16], sw[16];
#pragma unroll
    for (int i = 0; i < 16; ++i) {
        unsigned long long pv = __hip_atomic_load(
            part + ((((size_t)(p << 4) | b) << 4 | i) << 10) + tid,
            __ATOMIC_RELAXED, __HIP_MEMORY_SCOPE_AGENT);
        float2 ms;
        __builtin_memcpy(&ms, &pv, 8);
        mv[i] = ms.x; sw[i] = ms.y;
    }
    float M = mv[0];
#pragma unroll
    for (int i = 1; i < 16; ++i) M = fmaxf(M, mv[i]);
    float acc = 0.f;
#pragma unroll
    for (int i = 0; i < 16; ++i) acc = fmaf(sw[i], fexp2(mv[i] - M), acc);
    return UAB - EPSLN2 * (M + flog2(acc));
}

//==================== persistent all-LDS Sinkhorn: one block per (batch, 64-row slab)
// Plain (non-cooperative) launch: 256 blocks @ 1 block/CU are all co-resident;
// inter-block sync is hand-rolled agent-scope flags. Static LDS -> capture-safe.
__global__ __launch_bounds__(1024, 1)
void sinkhorn_lds(const float* __restrict__ x, const float* __restrict__ y,
                  unsigned long long* __restrict__ part,
                  float* __restrict__ udiffg, float* __restrict__ dslot,
                  unsigned int* __restrict__ arriveg,
                  unsigned int* __restrict__ sflag,
                  unsigned int* __restrict__ sflag2,
                  float* __restrict__ dsum,
                  float* __restrict__ out)
{
    __shared__ __align__(16) char smem[SMEM_BYTES];
    __half* Cs    = (__half*)smem;                  // [64][1024] fp16 slab
    float* vS     = (float*)(smem + OFF_VS);
    float* xstage = (float*)(smem + OFF_XST);
    float* snapV  = (float*)(smem + OFF_SNAPV);     // [2][1024]
    float2* fold  = (float2*)(smem + OFF_FOLD);     // [512]
    float* uS     = (float*)(smem + OFF_US);
    float* uS2    = (float*)(smem + OFF_US2);
    float* snapU  = (float*)(smem + OFF_SNAPU);     // [2][64]
    float* red    = (float*)(smem + OFF_RED);
    float* udiffL = (float*)(smem + OFF_UDL);
    float* misc   = (float*)(smem + OFF_MISC);
    float* xnS    = (float*)(smem + OFF_XN);

    const int tid  = threadIdx.x;
    const int lane = tid & 63;
    const int wv   = tid >> 6;
    const int bid  = blockIdx.x;
    // XCD-friendly mapping: batch b's 16 blocks share bid%8
    const int c = bid & 7, kk = bid >> 3;
    const int s = kk & 15;
    const int b = ((kk >> 4) << 3) | c;
    const int rb = wv << 2;                          // wave's 4 rows (phase A)
    // phase-A2 split: all 1024 threads, 2 cols x 32-row half-slab
    const int hh  = tid >> 9;
    const int idx = tid & 511;
    const int j0  = idx << 1;
    const int rlo = hh << 5;

    //---------------- build: stage x slab (64 rows x 64 d), zero u,v
    ((float4*)xstage)[tid] =
        ((const float4*)(x + (((size_t)(b << 10) + (s << 6)) << 6)))[tid];
    vS[tid] = 0.f;
    __syncthreads();
    if (tid < 64) {
        float a = 0.f;
        for (int d = 0; d < 64; d += 4) {
            float4 q = *(const float4*)(xstage + (tid << 6) + d);
            a = fmaf(q.x, q.x, a); a = fmaf(q.y, q.y, a);
            a = fmaf(q.z, q.z, a); a = fmaf(q.w, q.w, a);
        }
        xnS[tid] = a;
        uS[tid] = 0.f;
        uS2[tid] = 0.f;
    }
    __syncthreads();
    // build C slab into LDS: C_ij = |x_i|^2 + |y_j|^2 - 2 x.y
    for (int st = 0; st < 16; ++st) {
        const float* yp = y + (((size_t)(b << 10) + (st << 6) + lane) << 6);
        float acc0 = 0, acc1 = 0, acc2 = 0, acc3 = 0, yn = 0;
        for (int d8 = 0; d8 < 64; d8 += 8) {
            float xv[4][8];
#pragma unroll
            for (int r = 0; r < 4; ++r) {
                float4 A  = *(const float4*)(xstage + ((rb + r) << 6) + d8);
                float4 Bq = *(const float4*)(xstage + ((rb + r) << 6) + d8 + 4);
                xv[r][0] = A.x;  xv[r][1] = A.y;  xv[r][2] = A.z;  xv[r][3] = A.w;
                xv[r][4] = Bq.x; xv[r][5] = Bq.y; xv[r][6] = Bq.z; xv[r][7] = Bq.w;
            }
            float4 ya = *(const float4*)(yp + d8);
            float4 yb = *(const float4*)(yp + d8 + 4);
            float yv[8] = { ya.x, ya.y, ya.z, ya.w, yb.x, yb.y, yb.z, yb.w };
#pragma unroll
            for (int dd = 0; dd < 8; ++dd) {
                const float yd = yv[dd];
                yn   = fmaf(yd, yd, yn);
                acc0 = fmaf(xv[0][dd], yd, acc0);
                acc1 = fmaf(xv[1][dd], yd, acc1);
                acc2 = fmaf(xv[2][dd], yd, acc2);
                acc3 = fmaf(xv[3][dd], yd, acc3);
            }
        }
        const int col = (st << 6) + lane;
        Cs[((rb + 0) << 10) + col] = __float2half(xnS[rb + 0] + yn - 2.f * acc0);
        Cs[((rb + 1) << 10) + col] = __float2half(xnS[rb + 1] + yn - 2.f * acc1);
        Cs[((rb + 2) << 10) + col] = __float2half(xnS[rb + 2] + yn - 2.f * acc2);
        Cs[((rb + 3) << 10) + col] = __float2half(xnS[rb + 3] + yn - 2.f * acc3);
    }
    __syncthreads();   // xstage dead from here; snapV/fold overlay it

    // phase-A lse normalizer guesses (-inf forces exact path at it 0)
    float gRow[4] = { -INFINITY, -INFINITY, -INFINITY, -INFINITY };

    //---------------- Sinkhorn loop (speculative early-stop, lag 2)
    int it = 0;
    bool rolled = false;
    for (; it < MAXIT; ++it) {
        const int p = it & 1;
        // snapshot state-after-(it-1) into ring slot (it-1)&1
        if (it >= 1) {
            snapV[(((it - 1) & 1) << 10) + tid] = vS[tid];
            if (tid < 64) snapU[(((it - 1) & 1) << 6) + tid] = uS[tid];
        }
        // lag-2 verdict check (usually non-blocking)
        if (it >= 2) {
            if (tid == 0) {
                while (__hip_atomic_load(arriveg + ((it - 2) << 4),
                        __ATOMIC_RELAXED, __HIP_MEMORY_SCOPE_AGENT) < 16u)
                    __builtin_amdgcn_s_sleep(2);
                misc[0] = __hip_atomic_load(dslot + ((it - 2) << 4),
                        __ATOMIC_RELAXED, __HIP_MEMORY_SCOPE_AGENT);
            }
            __syncthreads();
            if (misc[0] * 0.0625f < THRESH) {
                vS[tid] = snapV[(((it - 2) & 1) << 10) + tid];
                if (tid < 64) uS[tid] = snapU[(((it - 2) & 1) << 6) + tid];
                __syncthreads();
                rolled = true;
                break;
            }
        }
        //---- phase A: u_i = UAB - eps*lse_j((v_j - C_ij)/eps)  [block-local]
        {
            float sv[16];
            {
                float4 a0 = ((const float4*)vS)[(lane << 1)];
                float4 a1 = ((const float4*)vS)[(lane << 1) + 1];
                float4 a2 = ((const float4*)vS)[128 + (lane << 1)];
                float4 a3 = ((const float4*)vS)[129 + (lane << 1)];
                sv[0] = a0.x * S2; sv[1] = a0.y * S2; sv[2] = a0.z * S2; sv[3] = a0.w * S2;
                sv[4] = a1.x * S2; sv[5] = a1.y * S2; sv[6] = a1.z * S2; sv[7] = a1.w * S2;
                sv[8]  = a2.x * S2; sv[9]  = a2.y * S2; sv[10] = a2.z * S2; sv[11] = a2.w * S2;
                sv[12] = a3.x * S2; sv[13] = a3.y * S2; sv[14] = a3.z * S2; sv[15] = a3.w * S2;
            }
            float ud4 = 0.f;
#pragma unroll
            for (int r4 = 0; r4 < 4; ++r4) {
                const int r = rb + r4;
                float4 ha = ((const float4*)(Cs + (r << 10)))[lane];
                float4 hb = ((const float4*)(Cs + (r << 10)))[64 + lane];
                float cf[16];
                unpack8(ha, cf); unpack8(hb, cf + 8);
                float a[16];
                const float g = gRow[r4];
                float ss = 0.f;
#pragma unroll
                for (int q = 0; q < 16; ++q) {
                    a[q] = fmaf(cf[q], -S2, sv[q]);
                    ss += fexp2(a[q] - g);
                }
#pragma unroll
                for (int off = 32; off; off >>= 1) ss += __shfl_xor(ss, off, 64);
                float gu = g;
                if (!sum_ok(ss)) {   // wave-uniform; fires at it 0 only (g=-inf)
                    float mx = a[0];
#pragma unroll
                    for (int q = 1; q < 16; ++q) mx = fmaxf(mx, a[q]);
#pragma unroll
                    for (int off = 32; off; off >>= 1)
                        mx = fmaxf(mx, __shfl_xor(mx, off, 64));
                    ss = 0.f;
#pragma unroll
                    for (int q = 0; q < 16; ++q) ss += fexp2(a[q] - mx);
#pragma unroll
                    for (int off = 32; off; off >>= 1) ss += __shfl_xor(ss, off, 64);
                    gu = mx;
                }
                const float lse = gu + flog2(ss);   // uniform across wave
                gRow[r4] = lse;                     // next iteration's guess
                if (lane == 0) {
                    const float un = UAB - EPSLN2 * lse;
                    ud4 += fabsf(un - uS[r]);
                    uS[r] = un;
                    uS2[r] = un * S2;
                }
            }
            if (lane == 0) red[wv] = ud4;
        }
        __syncthreads();
        if (tid == 0) {
            float t = 0.f;
#pragma unroll
            for (int g = 0; g < 16; ++g) t += red[g];
            __hip_atomic_store(udiffg + (p << 8) + (b << 4) + s, t,
                               __ATOMIC_RELAXED, __HIP_MEMORY_SCOPE_AGENT);
        }

        float vn;
        if (it == 0) {
            vn = ms_exchange(Cs, uS2, part, sflag2, p, b, s, it, tid);
        } else {
            //---- phase A2 (sum path): shared normalizer = prev column lse
            {
                const float g0 = (UAB - vS[j0])     * S2;
                const float g1 = (UAB - vS[j0 + 1]) * S2;
                float s0 = 0.f, s1 = 0.f;
                for (int r = rlo; r < rlo + 32; ++r) {
                    const float su = uS2[r];
                    float2 fc = __half22float2(*(const __half2*)(Cs + (r << 10) + j0));
                    s0 += fexp2(fmaf(fc.x, -S2, su) - g0);
                    s1 += fexp2(fmaf(fc.y, -S2, su) - g1);
                }
                if (hh == 1) fold[idx] = make_float2(s0, s1);
                __syncthreads();
                if (hh == 0) {
                    float2 o = fold[idx];
                    float* db = dsum + (((size_t)it << 4 | b) << 10);
                    __hip_atomic_fetch_add(db + j0,     s0 + o.x,
                        __ATOMIC_RELAXED, __HIP_MEMORY_SCOPE_AGENT);
                    __hip_atomic_fetch_add(db + j0 + 1, s1 + o.y,
                        __ATOMIC_RELAXED, __HIP_MEMORY_SCOPE_AGENT);
                }
            }
            __syncthreads();   // drain atomic adds (vmcnt) before flag
            if (tid == 0)
                __hip_atomic_store(sflag + ((((p << 4) | b) << 4 | s) << 4),
                                   (unsigned)(it + 1),
                                   __ATOMIC_RELEASE, __HIP_MEMORY_SCOPE_AGENT);
            if (tid < 16) {
                while (__hip_atomic_load(sflag + ((((p << 4) | b) << 4 | tid) << 4),
                        __ATOMIC_RELAXED, __HIP_MEMORY_SCOPE_AGENT) < (unsigned)(it + 1))
                    __builtin_amdgcn_s_sleep(1);
            }
            __syncthreads();
            //---- phase B (sum path): v from totals, uniform range check
            const float total = __hip_atomic_load(
                dsum + (((size_t)it << 4 | b) << 10) + tid,
                __ATOMIC_RELAXED, __HIP_MEMORY_SCOPE_AGENT);
            const float gj = (UAB - vS[tid]) * S2;
            // single-barrier block-wide AND of per-thread range checks
            if (__syncthreads_and(sum_ok(total) ? 1 : 0)) {
                vn = UAB - EPSLN2 * (gj + flog2(total));
            } else {
                vn = ms_exchange(Cs, uS2, part, sflag2, p, b, s, it, tid);
            }
        }
        //---- common tail: v write, diff reduce, verdict publish
        {
            float vd = fabsf(vn - vS[tid]);
            vS[tid] = vn;
#pragma unroll
            for (int off = 32; off; off >>= 1) vd += __shfl_xor(vd, off, 64);
            if (lane == 0) red[wv] = vd;
        }
        if (tid < 16 && s == 0)
            udiffL[tid] = __hip_atomic_load(udiffg + (p << 8) + (b << 4) + tid,
                                            __ATOMIC_RELAXED, __HIP_MEMORY_SCOPE_AGENT);
        __syncthreads();
        if (tid == 0 && s == 0) {
            float tot = 0.f;
#pragma unroll
            for (int g = 0; g < 16; ++g) tot += udiffL[g] + red[g];
            __hip_atomic_fetch_add(dslot + (it << 4), tot,
                                   __ATOMIC_RELAXED, __HIP_MEMORY_SCOPE_AGENT);
            __hip_atomic_fetch_add(arriveg + (it << 4), 1u,
                                   __ATOMIC_RELEASE, __HIP_MEMORY_SCOPE_AGENT);
        }
        __syncthreads();
    }

    // reached MAXIT: verdict for MAXIT-2 still unconsumed — may require rollback
    if (!rolled && it == MAXIT) {
        if (tid == 0) {
            while (__hip_atomic_load(arriveg + ((MAXIT - 2) << 4),
                    __ATOMIC_RELAXED, __HIP_MEMORY_SCOPE_AGENT) < 16u)
                __builtin_amdgcn_s_sleep(2);
            misc[0] = __hip_atomic_load(dslot + ((MAXIT - 2) << 4),
                    __ATOMIC_RELAXED, __HIP_MEMORY_SCOPE_AGENT);
        }
        __syncthreads();
        if (misc[0] * 0.0625f < THRESH) {
            vS[tid] = snapV[(((MAXIT - 2) & 1) << 10) + tid];
            if (tid < 64) uS[tid] = snapU[(((MAXIT - 2) & 1) << 6) + tid];
            __syncthreads();
        }
    }

    //---------------- cost: out[b] += sum over slab of exp2(S2(u+v-C))*C
    __syncthreads();
    {
        float sv[16];
        {
            float4 a0 = ((const float4*)vS)[(lane << 1)];
            float4 a1 = ((const float4*)vS)[(lane << 1) + 1];
            float4 a2 = ((const float4*)vS)[128 + (lane << 1)];
            float4 a3 = ((const float4*)vS)[129 + (lane << 1)];
            sv[0] = a0.x * S2; sv[1] = a0.y * S2; sv[2] = a0.z * S2; sv[3] = a0.w * S2;
            sv[4] = a1.x * S2; sv[5] = a1.y * S2; sv[6] = a1.z * S2; sv[7] = a1.w * S2;
            sv[8]  = a2.x * S2; sv[9]  = a2.y * S2; sv[10] = a2.z * S2; sv[11] = a2.w * S2;
            sv[12] = a3.x * S2; sv[13] = a3.y * S2; sv[14] = a3.z * S2; sv[15] = a3.w * S2;
        }
        float acc = 0.f;
#pragma unroll
        for (int r4 = 0; r4 < 4; ++r4) {
            const int r = rb + r4;
            const float su = uS[r] * S2;
            float4 ha = ((const float4*)(Cs + (r << 10)))[lane];
            float4 hb = ((const float4*)(Cs + (r << 10)))[64 + lane];
            float cf[16];
            unpack8(ha, cf); unpack8(hb, cf + 8);
#pragma unroll
            for (int q = 0; q < 16; ++q)
                acc = fmaf(fexp2(fmaf(cf[q], -S2, su + sv[q])), cf[q], acc);
        }
#pragma unroll
        for (int off = 32; off; off >>= 1) acc += __shfl_xor(acc, off, 64);
        if (lane == 0) red[wv] = acc;
        __syncthreads();
        if (tid == 0) {
            float t = 0.f;
#pragma unroll
            for (int g = 0; g < 16; ++g) t += red[g];
            atomicAdd(out + b, t);
        }
    }
}

//==================== small init for persistent path: zero counters + out
__global__ __launch_bounds__(256)
void init_small(unsigned int* __restrict__ zb, int nwords, float* __restrict__ out)
{
    const int gt = (blockIdx.x << 8) + threadIdx.x;
    for (int k = gt; k < nwords; k += gridDim.x << 8) zb[k] = 0u;
    if (gt < Bb) out[gt] = 0.f;
}

//==================== ---------- fallback path (round-4 proven) ----------
__global__ __launch_bounds__(256)
void init_kernel(const float* __restrict__ y, float* __restrict__ yT,
                 float* __restrict__ zbase, int zcount4)
{
    __shared__ float sm[64 * 65];
    const int tid = threadIdx.x;
    const int bid = blockIdx.x;
    if (bid < 256) {
        const int b  = bid >> 4;
        const int j0 = (bid & 15) << 6;
        const float4* src = (const float4*)(y + (size_t)(b * Mm + j0) * Dd);
#pragma unroll
        for (int k = 0; k < 4; ++k) {
            const int f4 = tid + (k << 8);
            float4 w = src[f4];
            const int f = f4 << 2;
            float* dst = sm + (f >> 6) * 65 + (f & 63);
            dst[0] = w.x; dst[1] = w.y; dst[2] = w.z; dst[3] = w.w;
        }
        __syncthreads();
        const int jj = tid & 63;
        const int db = tid >> 6;
#pragma unroll
        for (int k = 0; k < 16; ++k) {
            const int d = db + (k << 2);
            yT[(size_t)(b * Dd + d) * Mm + j0 + jj] = sm[jj * 65 + d];
        }
    } else {
        float4* z = (float4*)zbase;
        for (int k = ((bid - 256) << 8) + tid; k < zcount4; k += 65536)
            z[k] = make_float4(0.f, 0.f, 0.f, 0.f);
    }
}

__global__ __launch_bounds__(256)
void cbuild_kernel(const float* __restrict__ x, const float* __restrict__ yT,
                   __half* __restrict__ C, __half* __restrict__ CT)
{
    __shared__ float xs2[2048];
    __shared__ float xn[32];
    __shared__ __align__(16) __half tile[32 * 264];
    const int tid = threadIdx.x;
    const int t   = blockIdx.x;
    const int b   = t >> 7;
    const int rm  = t & 127;
    const int i0  = (rm >> 2) << 5;
    const int j0  = (rm & 3) << 8;
    const float4* xsrc = (const float4*)(x + (size_t)(b * Nn + i0) * Dd);
#pragma unroll
    for (int k = 0; k < 2; ++k) {
        const int f4 = tid + (k << 8);
        float4 w = xsrc[f4];
        float* dst = xs2 + (f4 << 2);
        dst[0] = -2.f * w.x; dst[1] = -2.f * w.y;
        dst[2] = -2.f * w.z; dst[3] = -2.f * w.w;
    }
    __syncthreads();
    if (tid < 32) {
        float a = 0.f;
        for (int d = 0; d < 64; ++d) { float q = xs2[tid * 64 + d]; a = fmaf(q, q, a); }
        xn[tid] = 0.25f * a;
    }
    __syncthreads();
    float acc[32];
#pragma unroll
    for (int ii = 0; ii < 32; ++ii) acc[ii] = 0.f;
    float yn = 0.f;
    const float* yTb = yT + (size_t)b * Dd * Mm + j0 + tid;
    for (int d4 = 0; d4 < 64; d4 += 4) {
        const float y0 = yTb[(size_t)(d4 + 0) * Mm];
        const float y1 = yTb[(size_t)(d4 + 1) * Mm];
        const float y2 = yTb[(size_t)(d4 + 2) * Mm];
        const float y3 = yTb[(size_t)(d4 + 3) * Mm];
        yn = fmaf(y0, y0, yn); yn = fmaf(y1, y1, yn);
        yn = fmaf(y2, y2, yn); yn = fmaf(y3, y3, yn);
#pragma unroll
        for (int ii = 0; ii < 32; ++ii) {
            const float4 xq = *(const float4*)(xs2 + ii * 64 + d4);
            acc[ii] = fmaf(xq.x, y0, acc[ii]);
            acc[ii] = fmaf(xq.y, y1, acc[ii]);
            acc[ii] = fmaf(xq.z, y2, acc[ii]);
            acc[ii] = fmaf(xq.w, y3, acc[ii]);
        }
    }
#pragma unroll
    for (int ii = 0; ii < 32; ++ii) acc[ii] += xn[ii] + yn;
#pragma unroll
    for (int ii = 0; ii < 32; ++ii) tile[ii * 264 + tid] = __float2half(acc[ii]);
    __syncthreads();
#pragma unroll
    for (int p = 0; p < 4; ++p) {
        const int r  = (p << 3) + (tid >> 5);
        const int c8 = (tid & 31) << 3;
        float4 w = *(const float4*)(tile + r * 264 + c8);
        *(float4*)(C + (((size_t)((b << 10) + i0 + r)) << 10) + j0 + c8) = w;
    }
    __half* CTout = CT + ((size_t)((b << 10) + j0 + tid) << 10) + i0;
#pragma unroll
    for (int g = 0; g < 4; ++g) {
        float4 w;
        __half2* hp = (__half2*)&w;
        hp[0] = __floats2half2_rn(acc[8 * g + 0], acc[8 * g + 1]);
        hp[1] = __floats2half2_rn(acc[8 * g + 2], acc[8 * g + 3]);
        hp[2] = __floats2half2_rn(acc[8 * g + 4], acc[8 * g + 5]);
        hp[3] = __floats2half2_rn(acc[8 * g + 6], acc[8 * g + 7]);
        ((float4*)CTout)[g] = w;
    }
}

__global__ __launch_bounds__(256)
void sweep_row(const __half* __restrict__ Cmat, const float* __restrict__ src,
               float* __restrict__ dst, float* __restrict__ dslots, int it)
{
    __shared__ float smw[4];
    const int tid  = threadIdx.x;
    const int lane = tid & 63;
    const int wv   = tid >> 6;
    const int row0 = (blockIdx.x << 3) | (wv << 1);
    const int b    = row0 >> 10;

    if (it > 0) {
        float tv = dslots[((it - 1) << 10) + (lane << 4)];
#pragma unroll
        for (int off = 32; off; off >>= 1) tv += __shfl_xor(tv, off, 64);
        if (tv * (1.f / 16.f) < THRESH) return;
    }

    const float4* s4 = (const float4*)(src + (b << 10));
    float4 sv0 = s4[(lane << 1)];
    float4 sv1 = s4[(lane << 1) + 1];
    float4 sv2 = s4[128 + (lane << 1)];
    float4 sv3 = s4[129 + (lane << 1)];
    float svs[16];
    svs[0] = sv0.x * S2; svs[1] = sv0.y * S2; svs[2] = sv0.z * S2; svs[3] = sv0.w * S2;
    svs[4] = sv1.x * S2; svs[5] = sv1.y * S2; svs[6] = sv1.z * S2; svs[7] = sv1.w * S2;
    svs[8]  = sv2.x * S2; svs[9]  = sv2.y * S2; svs[10] = sv2.z * S2; svs[11] = sv2.w * S2;
    svs[12] = sv3.x * S2; svs[13] = sv3.y * S2; svs[14] = sv3.z * S2; svs[15] = sv3.w * S2;

    const float4* c4 = (const float4*)(Cmat + ((size_t)row0 << 10));
    float4 ca0 = c4[lane];
    float4 ca1 = c4[64 + lane];
    float4 cb0 = c4[128 + lane];
    float4 cb1 = c4[192 + lane];
    float cf[32];
    unpack8(ca0, cf);      unpack8(ca1, cf + 8);
    unpack8(cb0, cf + 16); unpack8(cb1, cf + 24);

    float a0[16], a1[16];
    float m0 = -INFINITY, m1 = -INFINITY;
#pragma unroll
    for (int k = 0; k < 16; ++k) {
        a0[k] = fmaf(cf[k],      -S2, svs[k]);
        a1[k] = fmaf(cf[16 + k], -S2, svs[k]);
        m0 = fmaxf(m0, a0[k]);
        m1 = fmaxf(m1, a1[k]);
    }
#pragma unroll
    for (int off = 32; off; off >>= 1) {
        m0 = fmaxf(m0, __shfl_xor(m0, off, 64));
        m1 = fmaxf(m1, __shfl_xor(m1, off, 64));
    }
    float s0 = 0.f, s1 = 0.f;
#pragma unroll
    for (int k = 0; k < 16; ++k) { s0 += exp2f(a0[k] - m0); s1 += exp2f(a1[k] - m1); }
#pragma unroll
    for (int off = 32; off; off >>= 1) {
        s0 += __shfl_xor(s0, off, 64);
        s1 += __shfl_xor(s1, off, 64);
    }
    if (lane == 0) {
        const float dn0 = UAB - EPSLN2 * (m0 + log2f(s0));
        const float dn1 = UAB - EPSLN2 * (m1 + log2f(s1));
        float* dp = dst + row0;
        const float dd = fabsf(dn0 - dp[0]) + fabsf(dn1 - dp[1]);
        dp[0] = dn0; dp[1] = dn1;
        smw[wv] = dd;
    }
    __syncthreads();
    if (tid == 0) {
        const float bd = smw[0] + smw[1] + smw[2] + smw[3];
        atomicAdd(dslots + (it << 10) + ((blockIdx.x & 63) << 4), bd);
    }
}

__global__ __launch_bounds__(256)
void cost_kernel(const __half* __restrict__ C, const float* __restrict__ u,
                 const float* __restrict__ v, float* __restrict__ cpart)
{
    __shared__ float sm[4];
    const int tid  = threadIdx.x;
    const int lane = tid & 63;
    const int wv   = tid >> 6;
    const int row  = (blockIdx.x << 2) | wv;
    const int b    = row >> 10;
    const float ui = u[row];

    const float4* s4 = (const float4*)(v + (b << 10));
    float4 sv0 = s4[(lane << 1)];
    float4 sv1 = s4[(lane << 1) + 1];
    float4 sv2 = s4[128 + (lane << 1)];
    float4 sv3 = s4[129 + (lane << 1)];
    float vv[16];
    vv[0] = sv0.x; vv[1] = sv0.y; vv[2]  = sv0.z; vv[3]  = sv0.w;
    vv[4] = sv1.x; vv[5] = sv1.y; vv[6]  = sv1.z; vv[7]  = sv1.w;
    vv[8] = sv2.x; vv[9] = sv2.y; vv[10] = sv2.z; vv[11] = sv2.w;
    vv[12] = sv3.x; vv[13] = sv3.y; vv[14] = sv3.z; vv[15] = sv3.w;

    const float4* c4 = (const float4*)(C + ((size_t)row << 10));
    float cf[16];
    unpack8(c4[lane], cf);
    unpack8(c4[64 + lane], cf + 8);

    float acc = 0.f;
#pragma unroll
    for (int k = 0; k < 16; ++k)
        acc = fmaf(exp2f((ui + vv[k] - cf[k]) * S2), cf[k], acc);
#pragma unroll
    for (int off = 32; off; off >>= 1) acc += __shfl_xor(acc, off, 64);
    if (lane == 0) sm[wv] = acc;
    __syncthreads();
    if (tid == 0) cpart[blockIdx.x] = sm[0] + sm[1] + sm[2] + sm[3];
}

__global__ __launch_bounds__(256)
void cost_fin(const float* __restrict__ cpart, float* __restrict__ out)
{
    __shared__ float sm[4];
    const int tid  = threadIdx.x;
    const int lane = tid & 63;
    const int wv   = tid >> 6;
    float vpt = cpart[(blockIdx.x << 8) + tid];
#pragma unroll
    for (int off = 32; off; off >>= 1) vpt += __shfl_xor(vpt, off, 64);
    if (lane == 0) sm[wv] = vpt;
    __syncthreads();
    if (tid == 0) out[blockIdx.x] = sm[0] + sm[1] + sm[2] + sm[3];
}

extern "C" void kernel_launch(void* const* d_in, const int* in_sizes, int n_in,
                              void* d_out, int out_size, void* d_ws, size_t ws_size,
                              hipStream_t stream) {
    const float* x = (const float*)d_in[0];
    const float* y = (const float*)d_in[1];
    float* out = (float*)d_out;

    // ---- fallback region layout (round-4)
    const size_t nCh  = (size_t)Bb * Nn * Mm;
    const size_t nyT  = (size_t)Bb * Dd * Mm;
    const size_t nu   = (size_t)Bb * Nn;
    const size_t nv   = (size_t)Bb * Mm;
    const size_t nds  = (size_t)MAXIT * SLOTS_PER_IT;
    const size_t nbar = 1024;
    const size_t ncp  = 4096;
    const size_t fb_bytes = 2 * nCh * sizeof(__half) +
                            (nyT + nu + nv + nds + nbar + ncp) * sizeof(float);
    __half* C  = (__half*)d_ws;
    __half* CT = C + nCh;
    float*  yT = (float*)(CT + nCh);
    float*  u  = yT + nyT;
    float*  v  = u + nu;
    float*  ds = v + nv;
    float*  cp = ds + nds + nbar;

    // ---- persist-path region (after fallback region, 8B aligned)
    size_t off = (fb_bytes + 7) & ~(size_t)7;
    unsigned long long* part = (unsigned long long*)((char*)d_ws + off);
    off += (size_t)2 * 16 * 16 * 1024 * 8;                 // 4 MB
    float* udiffg = (float*)((char*)d_ws + off);  off += 512 * 4;
    // zero-region start: dslot2, arriveg, sflag, sflag2, dsum contiguous
    float* dslot2 = (float*)((char*)d_ws + off);  off += (size_t)MAXIT * 16 * 4;
    unsigned int* arriveg = (unsigned int*)((char*)d_ws + off); off += (size_t)MAXIT * 16 * 4;
    unsigned int* sflag   = (unsigned int*)((char*)d_ws + off); off += (size_t)2 * 16 * 16 * 16 * 4;
    unsigned int* sflag2  = (unsigned int*)((char*)d_ws + off); off += (size_t)2 * 16 * 16 * 16 * 4;
    float* dsum = (float*)((char*)d_ws + off); off += (size_t)MAXIT * 16 * 1024 * 4;  // 6.55 MB
    const size_t need_bytes = off;
    const int nzwords = MAXIT * 16 + MAXIT * 16 + 2 * (2 * 16 * 16 * 16) +
                        MAXIT * 16 * 1024;

    bool done = false;
    if (ws_size >= need_bytes) {
        hipLaunchKernelGGL(init_small, dim3(256), dim3(256), 0, stream,
                           (unsigned int*)dslot2, nzwords, out);
        // Plain (non-cooperative) launch: static 153 KB LDS, 1 block/CU,
        // 256 blocks == 256 CUs -> all co-resident; graph-capture safe.
        hipLaunchKernelGGL(sinkhorn_lds, dim3(256), dim3(1024), 0, stream,
                           x, y, part, udiffg, dslot2, arriveg, sflag, sflag2,
                           dsum, out);
        done = (hipGetLastError() == hipSuccess);
    }
    if (!done) {
        // round-4 proven fallback chain
        const int zcount4 = (int)((nu + nv + nds + nbar) >> 2);
        hipLaunchKernelGGL(init_kernel, dim3(512), dim3(256), 0, stream,
                           y, yT, u, zcount4);
        hipLaunchKernelGGL(cbuild_kernel, dim3(2048), dim3(256), 0, stream,
                           x, yT, C, CT);
        for (int it = 0; it < MAXIT; ++it) {
            hipLaunchKernelGGL(sweep_row, dim3(2048), dim3(256), 0, stream,
                               C, v, u, ds, it);
            hipLaunchKernelGGL(sweep_row, dim3(2048), dim3(256), 0, stream,
                               CT, u, v, ds, it);
        }
        hipLaunchKernelGGL(cost_kernel, dim3(4096), dim3(256), 0, stream,
                           C, u, v, cp);
        hipLaunchKernelGGL(cost_fin, dim3(16), dim3(256), 0, stream, cp, out);
    }
}